// Round 1
// baseline (1036.490 us; speedup 1.0000x reference)
//
#include <hip/hip_runtime.h>
#include <math.h>

#define NN 20000   // nodes
#define NE 320000  // edges (without self-loops)
#define TT 8       // timesteps
#define D1 256     // H*F layer-1 width
#define CD 32      // layer-2 width == LSTM hidden

// ---------------- CSR build (once per launch; edges identical across t) ----------------

__global__ __launch_bounds__(256) void k_deg(const int* __restrict__ dst, int* __restrict__ deg) {
  int e = blockIdx.x * 256 + threadIdx.x;
  if (e < NE) atomicAdd(&deg[dst[e]], 1);
}

__global__ __launch_bounds__(1024) void k_scan(const int* __restrict__ deg,
                                               int* __restrict__ rowptr, int* __restrict__ fill) {
  __shared__ int sd[1024];
  __shared__ int carry_s;
  int tid = threadIdx.x;
  if (tid == 0) { carry_s = 0; rowptr[0] = 0; }
  __syncthreads();
  for (int base = 0; base < NN; base += 1024) {
    int i = base + tid;
    int v = (i < NN) ? deg[i] : 0;
    sd[tid] = v;
    __syncthreads();
    for (int off = 1; off < 1024; off <<= 1) {
      int t = (tid >= off) ? sd[tid - off] : 0;
      __syncthreads();
      sd[tid] += t;
      __syncthreads();
    }
    int incl = sd[tid];
    int carry = carry_s;
    if (i < NN) { rowptr[i + 1] = carry + incl; fill[i] = carry + incl - v; }
    __syncthreads();
    if (tid == 1023) carry_s = carry + sd[1023];
    __syncthreads();
  }
}

__global__ __launch_bounds__(256) void k_fill(const int* __restrict__ src, const int* __restrict__ dst,
                                              int* __restrict__ fill, int* __restrict__ csr) {
  int e = blockIdx.x * 256 + threadIdx.x;
  if (e < NE) {
    int pos = atomicAdd(&fill[dst[e]], 1);
    csr[pos] = src[e];
  }
}

// ---------------- one-time: folded attention vectors + weight transposes --------------------

__global__ __launch_bounds__(256) void k_prew(const float* __restrict__ W1,
    const float* __restrict__ as1, const float* __restrict__ ad1,
    const float* __restrict__ W2,
    float* __restrict__ wsrc, float* __restrict__ wdst,
    float* __restrict__ W1T, float* __restrict__ W2T) {
  int tid = threadIdx.x;
  int k = tid >> 3, h = tid & 7;
  float s = 0.f, d = 0.f;
  #pragma unroll
  for (int f = 0; f < 32; ++f) {
    float wv = W1[k * D1 + h * 32 + f];
    s = fmaf(wv, as1[h * 32 + f], s);
    d = fmaf(wv, ad1[h * 32 + f], d);
  }
  wsrc[k * 8 + h] = s;
  wdst[k * 8 + h] = d;
  for (int i = tid; i < D1 * 32; i += 256) {
    int j = i >> 5, kk = i & 31;
    W1T[i] = W1[kk * D1 + j];          // W1T[j*32+kk]
  }
  for (int i = tid; i < 32 * D1; i += 256) {
    int f = i >> 8, kk = i & 255;
    W2T[i] = W2[kk * CD + f];          // W2T[f*256+kk]
  }
}

// ---------------- logits for all t: als/ald = x @ w~ ; t = blockIdx.x & 7 -------------------

__global__ __launch_bounds__(256) void k_logits8(const float* __restrict__ x,
    const float* __restrict__ wsrc, const float* __restrict__ wdst,
    float* __restrict__ als, float* __restrict__ ald) {
  __shared__ float xs[32 * 33];
  __shared__ float wsr[256], wdr[256];
  int tid = threadIdx.x;
  int t = blockIdx.x & 7;
  int n0 = (blockIdx.x >> 3) * 32;
  const float* xt = x + (size_t)t * NN * 32;
  int nl = tid >> 3, h = tid & 7;
  for (int i = tid; i < 1024; i += 256) {
    int g = i >> 5, k = i & 31;
    xs[g * 33 + k] = xt[n0 * 32 + i];
  }
  wsr[tid] = wsrc[tid];
  wdr[tid] = wdst[tid];
  __syncthreads();
  const float* xr = xs + nl * 33;
  float as = 0.f, ad = 0.f;
  #pragma unroll
  for (int k = 0; k < 32; ++k) {
    float xv = xr[k];
    as = fmaf(xv, wsr[k * 8 + h], as);
    ad = fmaf(xv, wdr[k * 8 + h], ad);
  }
  als[(size_t)t * NN * 8 + n0 * 8 + tid] = as;
  ald[(size_t)t * NN * 8 + n0 * 8 + tid] = ad;
}

// ---------------- layer-1 gather, ALL t in one wave: wave=node, lane=(t,h), 2-edge unroll ---

__global__ __launch_bounds__(256, 4) void k_gat1(const float* __restrict__ x,
    const float* __restrict__ als, const float* __restrict__ ald,
    const int* __restrict__ rowptr, const int* __restrict__ csr,
    float* __restrict__ aggx, float* __restrict__ den1) {
  int tid = threadIdx.x;
  int wv = tid >> 6, lane = tid & 63;
  int t = lane >> 3, h = lane & 7;
  int n = blockIdx.x * 4 + wv;
  const float* alst = als + (size_t)t * NN * 8 + h;           // + s*8 per edge
  float adv = ald[(size_t)t * NN * 8 + (size_t)n * 8 + h];
  const float4* x4t = (const float4*)(x + (size_t)t * NN * 32);
  float4 acc[8];
  #pragma unroll
  for (int q = 0; q < 8; ++q) acc[q] = make_float4(0.f, 0.f, 0.f, 0.f);
  float den = 0.f;
  int beg = rowptr[n], end = rowptr[n + 1];
  // virtual list [beg, end]: edges then self-loop at position `end`
  int v = beg;
  for (; v + 1 <= end; v += 2) {
    int s0 = csr[v];                              // v < end guaranteed here
    int s1 = (v + 1 < end) ? csr[v + 1] : n;
    float a0 = alst[(size_t)s0 * 8] + adv;
    float a1 = alst[(size_t)s1 * 8] + adv;
    const float4* xr0 = x4t + (size_t)s0 * 8;
    const float4* xr1 = x4t + (size_t)s1 * 8;
    a0 = fmaxf(a0, 0.2f * a0);
    a1 = fmaxf(a1, 0.2f * a1);
    float e0 = __expf(a0), e1 = __expf(a1);
    float4 u0 = xr0[0], u1 = xr0[1], u2 = xr0[2], u3 = xr0[3];
    float4 u4 = xr0[4], u5 = xr0[5], u6 = xr0[6], u7 = xr0[7];
    float4 w0 = xr1[0], w1 = xr1[1], w2 = xr1[2], w3 = xr1[3];
    float4 w4 = xr1[4], w5 = xr1[5], w6 = xr1[6], w7 = xr1[7];
    acc[0].x = fmaf(e1, w0.x, fmaf(e0, u0.x, acc[0].x));
    acc[0].y = fmaf(e1, w0.y, fmaf(e0, u0.y, acc[0].y));
    acc[0].z = fmaf(e1, w0.z, fmaf(e0, u0.z, acc[0].z));
    acc[0].w = fmaf(e1, w0.w, fmaf(e0, u0.w, acc[0].w));
    acc[1].x = fmaf(e1, w1.x, fmaf(e0, u1.x, acc[1].x));
    acc[1].y = fmaf(e1, w1.y, fmaf(e0, u1.y, acc[1].y));
    acc[1].z = fmaf(e1, w1.z, fmaf(e0, u1.z, acc[1].z));
    acc[1].w = fmaf(e1, w1.w, fmaf(e0, u1.w, acc[1].w));
    acc[2].x = fmaf(e1, w2.x, fmaf(e0, u2.x, acc[2].x));
    acc[2].y = fmaf(e1, w2.y, fmaf(e0, u2.y, acc[2].y));
    acc[2].z = fmaf(e1, w2.z, fmaf(e0, u2.z, acc[2].z));
    acc[2].w = fmaf(e1, w2.w, fmaf(e0, u2.w, acc[2].w));
    acc[3].x = fmaf(e1, w3.x, fmaf(e0, u3.x, acc[3].x));
    acc[3].y = fmaf(e1, w3.y, fmaf(e0, u3.y, acc[3].y));
    acc[3].z = fmaf(e1, w3.z, fmaf(e0, u3.z, acc[3].z));
    acc[3].w = fmaf(e1, w3.w, fmaf(e0, u3.w, acc[3].w));
    acc[4].x = fmaf(e1, w4.x, fmaf(e0, u4.x, acc[4].x));
    acc[4].y = fmaf(e1, w4.y, fmaf(e0, u4.y, acc[4].y));
    acc[4].z = fmaf(e1, w4.z, fmaf(e0, u4.z, acc[4].z));
    acc[4].w = fmaf(e1, w4.w, fmaf(e0, u4.w, acc[4].w));
    acc[5].x = fmaf(e1, w5.x, fmaf(e0, u5.x, acc[5].x));
    acc[5].y = fmaf(e1, w5.y, fmaf(e0, u5.y, acc[5].y));
    acc[5].z = fmaf(e1, w5.z, fmaf(e0, u5.z, acc[5].z));
    acc[5].w = fmaf(e1, w5.w, fmaf(e0, u5.w, acc[5].w));
    acc[6].x = fmaf(e1, w6.x, fmaf(e0, u6.x, acc[6].x));
    acc[6].y = fmaf(e1, w6.y, fmaf(e0, u6.y, acc[6].y));
    acc[6].z = fmaf(e1, w6.z, fmaf(e0, u6.z, acc[6].z));
    acc[6].w = fmaf(e1, w6.w, fmaf(e0, u6.w, acc[6].w));
    acc[7].x = fmaf(e1, w7.x, fmaf(e0, u7.x, acc[7].x));
    acc[7].y = fmaf(e1, w7.y, fmaf(e0, u7.y, acc[7].y));
    acc[7].z = fmaf(e1, w7.z, fmaf(e0, u7.z, acc[7].z));
    acc[7].w = fmaf(e1, w7.w, fmaf(e0, u7.w, acc[7].w));
    den += e0 + e1;
  }
  if (v <= end) {                                 // 1 leftover (edge or self-loop)
    int s = (v < end) ? csr[v] : n;
    float a = alst[(size_t)s * 8] + adv;
    a = fmaxf(a, 0.2f * a);
    float e = __expf(a);
    const float4* xr = x4t + (size_t)s * 8;
    #pragma unroll
    for (int q = 0; q < 8; ++q) {
      float4 xv = xr[q];
      acc[q].x = fmaf(e, xv.x, acc[q].x);
      acc[q].y = fmaf(e, xv.y, acc[q].y);
      acc[q].z = fmaf(e, xv.z, acc[q].z);
      acc[q].w = fmaf(e, xv.w, acc[q].w);
    }
    den += e;
  }
  float4* ao = (float4*)(aggx + ((size_t)t * NN + n) * 256 + h * 32);
  #pragma unroll
  for (int q = 0; q < 8; ++q) ao[q] = acc[q];
  den1[((size_t)t * NN + n) * 8 + h] = den;
}

// ---------------- dense epilogue: 8 nodes/block for 8 blocks/CU occupancy -------------------
// LDS 16.6 KB -> 8 blocks/CU (was 33 KB -> 4). Same per-thread register blocking (2 cols),
// rows/thread drops 8 -> 4. launch_bounds(256,8) pins VGPR<=64 (current build is exactly 64).

__global__ __launch_bounds__(256, 8) void k_post(const float* __restrict__ aggx,
    const float* __restrict__ den1, const float* __restrict__ W1T, const float* __restrict__ b1,
    const float* __restrict__ W2T, const float* __restrict__ as2, const float* __restrict__ ad2,
    float* __restrict__ h2, float* __restrict__ al2s, float* __restrict__ al2d) {
  __shared__ float aggs[8 * 256];    // phase-2 input; aliased as part[8][8][32] in phase 3
  __shared__ float rels[8 * 256];
  __shared__ float dens[8 * 8];      // INVERSE denominators
  float* part = aggs;                // 8*8*32 == 8*256 floats exactly
  int tid = threadIdx.x;
  int t = blockIdx.x & 7;
  int n0 = (blockIdx.x >> 3) * 8;

  const float4* ag4 = (const float4*)(aggx + ((size_t)t * NN + n0) * 256);
  float4* as4 = (float4*)aggs;
  #pragma unroll
  for (int k = 0; k < 2; ++k) as4[tid + k * 256] = ag4[tid + k * 256];
  if (tid < 64) dens[tid] = 1.f / den1[((size_t)t * NN + n0) * 8 + tid];

  int u = tid & 127, grp = tid >> 7;
  int j0 = 2 * u;
  int hj = j0 >> 5;
  float4 w1a[8], w1b[8];
  const float4* w1p = (const float4*)(W1T + j0 * 32);
  #pragma unroll
  for (int q8 = 0; q8 < 8; ++q8) { w1a[q8] = w1p[q8]; w1b[q8] = w1p[q8 + 8]; }
  float bj0 = b1[j0], bj1 = b1[j0 + 1];
  __syncthreads();

  // phase 2: rows grp*4..+3, columns j0, j0+1 (aggs reads shared by both columns)
  #pragma unroll
  for (int g = 0; g < 4; ++g) {
    int row = grp * 4 + g;
    const float4* ar4 = (const float4*)(aggs + row * 256 + hj * 32);
    float a0 = 0.f, a1 = 0.f;
    #pragma unroll
    for (int k4 = 0; k4 < 8; ++k4) {
      float4 av = ar4[k4];
      a0 = fmaf(av.x, w1a[k4].x, fmaf(av.y, w1a[k4].y,
           fmaf(av.z, w1a[k4].z, fmaf(av.w, w1a[k4].w, a0))));
      a1 = fmaf(av.x, w1b[k4].x, fmaf(av.y, w1b[k4].y,
           fmaf(av.z, w1b[k4].z, fmaf(av.w, w1b[k4].w, a1))));
    }
    float invd = dens[row * 8 + hj];
    float2 r;
    r.x = fmaxf(fmaf(a0, invd, bj0), 0.f);
    r.y = fmaxf(fmaf(a1, invd, bj1), 0.f);
    *(float2*)(rels + row * 256 + j0) = r;
  }
  __syncthreads();   // rels ready; aggs dead -> reuse as part

  // phase 3: q-split over K (8 chunks of 32), columns f0, f0+1
  int q = u >> 4, fp = u & 15, f0 = 2 * fp;
  float4 w2a[8], w2b[8];
  const float4* w2pa = (const float4*)(W2T + f0 * 256 + q * 32);
  const float4* w2pb = (const float4*)(W2T + (f0 + 1) * 256 + q * 32);
  #pragma unroll
  for (int q8 = 0; q8 < 8; ++q8) { w2a[q8] = w2pa[q8]; w2b[q8] = w2pb[q8]; }
  #pragma unroll
  for (int g = 0; g < 4; ++g) {
    int row = grp * 4 + g;
    const float4* r4 = (const float4*)(rels + row * 256 + q * 32);
    float a0 = 0.f, a1 = 0.f;
    #pragma unroll
    for (int jj = 0; jj < 8; ++jj) {
      float4 a4 = r4[jj];
      a0 = fmaf(a4.x, w2a[jj].x, fmaf(a4.y, w2a[jj].y,
           fmaf(a4.z, w2a[jj].z, fmaf(a4.w, w2a[jj].w, a0))));
      a1 = fmaf(a4.x, w2b[jj].x, fmaf(a4.y, w2b[jj].y,
           fmaf(a4.z, w2b[jj].z, fmaf(a4.w, w2b[jj].w, a1))));
    }
    float2 pr; pr.x = a0; pr.y = a1;
    *(float2*)(part + q * 256 + row * 32 + f0) = pr;
  }
  __syncthreads();

  // reduce over q + h2 write + layer-2 logits (single pass: 8 rows x 32 f = 256 threads)
  float as2f = as2[tid & 31], ad2f = ad2[tid & 31];
  int row = tid >> 5;
  int ff = tid & 31;
  float v = 0.f;
  #pragma unroll
  for (int qq = 0; qq < 8; ++qq) v += part[qq * 256 + row * 32 + ff];
  int nn = n0 + row;
  h2[((size_t)t * NN + nn) * CD + ff] = v;
  float vs = v * as2f, vd = v * ad2f;
  #pragma unroll
  for (int m = 1; m < 32; m <<= 1) {
    vs += __shfl_xor(vs, m, 64);
    vd += __shfl_xor(vd, m, 64);
  }
  if (ff == 0) {
    al2s[(size_t)t * NN + nn] = vs;
    al2d[(size_t)t * NN + nn] = vd;
  }
}

// ---------------- layer-2 aggregation, ALL t in one wave: lane=(t, f-quad), 2-edge unroll ---

__global__ __launch_bounds__(256, 8) void k_agg2(const float* __restrict__ h2,
    const float* __restrict__ al2s, const float* __restrict__ al2d,
    const int* __restrict__ rowptr, const int* __restrict__ csr,
    const float* __restrict__ b2, float* __restrict__ out) {
  int tid = threadIdx.x;
  int wv = tid >> 6, lane = tid & 63;
  int t = lane >> 3, p = lane & 7;
  int n = blockIdx.x * 4 + wv;
  const float* alst = al2s + (size_t)t * NN;
  float adv = al2d[(size_t)t * NN + n];
  const float4* h24 = (const float4*)h2 + (size_t)t * NN * 8 + p;
  float4 b4 = ((const float4*)b2)[p];
  float4 acc = make_float4(0.f, 0.f, 0.f, 0.f);
  float den = 0.f;
  int beg = rowptr[n], end = rowptr[n + 1];
  int v = beg;
  for (; v + 1 <= end; v += 2) {
    int s0 = csr[v];
    int s1 = (v + 1 < end) ? csr[v + 1] : n;
    float a0 = alst[s0] + adv;
    float a1 = alst[s1] + adv;
    float4 u = h24[(size_t)s0 * 8];
    float4 w = h24[(size_t)s1 * 8];
    a0 = fmaxf(a0, 0.2f * a0);
    a1 = fmaxf(a1, 0.2f * a1);
    float e0 = __expf(a0), e1 = __expf(a1);
    acc.x = fmaf(e1, w.x, fmaf(e0, u.x, acc.x));
    acc.y = fmaf(e1, w.y, fmaf(e0, u.y, acc.y));
    acc.z = fmaf(e1, w.z, fmaf(e0, u.z, acc.z));
    acc.w = fmaf(e1, w.w, fmaf(e0, u.w, acc.w));
    den += e0 + e1;
  }
  if (v <= end) {
    int s = (v < end) ? csr[v] : n;
    float a = alst[s] + adv;
    a = fmaxf(a, 0.2f * a);
    float e = __expf(a);
    float4 u = h24[(size_t)s * 8];
    acc.x = fmaf(e, u.x, acc.x);
    acc.y = fmaf(e, u.y, acc.y);
    acc.z = fmaf(e, u.z, acc.z);
    acc.w = fmaf(e, u.w, acc.w);
    den += e;
  }
  float inv = 1.f / den;
  float4 o;
  o.x = fmaf(acc.x, inv, b4.x);
  o.y = fmaf(acc.y, inv, b4.y);
  o.z = fmaf(acc.z, inv, b4.z);
  o.w = fmaf(acc.w, inv, b4.w);
  ((float4*)out)[((size_t)t * NN + n) * 8 + p] = o;
}

// ---------------- LSTM, all t in one kernel: weights in VGPRs, h/c in LDS ------------------

__global__ __launch_bounds__(256) void k_lstm_all(const float* __restrict__ agg2o,
    const float* __restrict__ w_ih, const float* __restrict__ w_hh,
    const float* __restrict__ b_ih, const float* __restrict__ b_hh,
    float* __restrict__ out) {
  __shared__ float xs[16 * 32], hs[16 * 32], cs[16 * 32], pre[16 * 128];
  int tid = threadIdx.x;
  int slot = tid >> 7;
  int r = tid & 127;
  float4 wi[8], wh[8];
  const float4* wi4 = (const float4*)(w_ih + r * 32);
  const float4* wh4 = (const float4*)(w_hh + r * 32);
  #pragma unroll
  for (int q = 0; q < 8; ++q) { wi[q] = wi4[q]; wh[q] = wh4[q]; }
  float bias = b_ih[r] + b_hh[r];
  int base = blockIdx.x * 16;
  for (int i = tid; i < 512; i += 256) { hs[i] = 0.f; cs[i] = 0.f; }
  for (int t = 0; t < TT; ++t) {
    for (int i = tid; i < 512; i += 256) xs[i] = agg2o[(size_t)t * NN * 32 + base * 32 + i];
    __syncthreads();
    #pragma unroll
    for (int g = 0; g < 8; ++g) {
      int nl = slot * 8 + g;
      const float4* xv4 = (const float4*)(xs + nl * 32);
      const float4* hv4 = (const float4*)(hs + nl * 32);
      float acc = bias;
      #pragma unroll
      for (int q = 0; q < 8; ++q) {
        float4 a = xv4[q], b = hv4[q];
        acc = fmaf(a.x, wi[q].x, acc);
        acc = fmaf(a.y, wi[q].y, acc);
        acc = fmaf(a.z, wi[q].z, acc);
        acc = fmaf(a.w, wi[q].w, acc);
        acc = fmaf(b.x, wh[q].x, acc);
        acc = fmaf(b.y, wh[q].y, acc);
        acc = fmaf(b.z, wh[q].z, acc);
        acc = fmaf(b.w, wh[q].w, acc);
      }
      pre[nl * 128 + r] = acc;
    }
    __syncthreads();
    for (int i = tid; i < 512; i += 256) {
      int nl = i >> 5, k = i & 31;
      float ai = pre[nl * 128 + k];
      float af = pre[nl * 128 + 32 + k];
      float ag = pre[nl * 128 + 64 + k];
      float ao = pre[nl * 128 + 96 + k];
      float ii = 1.f / (1.f + __expf(-ai));
      float ff = 1.f / (1.f + __expf(-af));
      float gg = tanhf(ag);
      float oo = 1.f / (1.f + __expf(-ao));
      float cn = fmaf(ff, cs[i], ii * gg);
      float hn = oo * tanhf(cn);
      cs[i] = cn; hs[i] = hn;
      out[(size_t)t * NN * 32 + base * 32 + i] = hn;
    }
  }
}

// ---------------- softmax over nodes, coalesced two-pass ----------------

__global__ __launch_bounds__(256) void k_sm_sum(const float* __restrict__ out, float* __restrict__ sums) {
  int t = blockIdx.y;
  const float4* b4 = (const float4*)(out + ((size_t)t * NN + blockIdx.x * 800) * CD);
  int tid = threadIdx.x;
  float4 s4 = make_float4(0.f, 0.f, 0.f, 0.f);
  for (int i = tid; i < 6400; i += 256) {
    float4 v = b4[i];
    s4.x += __expf(v.x); s4.y += __expf(v.y);
    s4.z += __expf(v.z); s4.w += __expf(v.w);
  }
  __shared__ float4 red[256];
  red[tid] = s4;
  __syncthreads();
  for (int off = 128; off >= 8; off >>= 1) {
    if (tid < off) {
      float4 o = red[tid + off];
      red[tid].x += o.x; red[tid].y += o.y; red[tid].z += o.z; red[tid].w += o.w;
    }
    __syncthreads();
  }
  if (tid < 8) {
    float4 v = red[tid];
    int c0 = tid * 4;
    atomicAdd(&sums[t * CD + c0 + 0], v.x);
    atomicAdd(&sums[t * CD + c0 + 1], v.y);
    atomicAdd(&sums[t * CD + c0 + 2], v.z);
    atomicAdd(&sums[t * CD + c0 + 3], v.w);
  }
}

__global__ __launch_bounds__(256) void k_sm_scale(float* __restrict__ out, const float* __restrict__ sums) {
  int t = blockIdx.y;
  __shared__ float inv[CD];
  int tid = threadIdx.x;
  if (tid < CD) inv[tid] = 1.f / sums[t * CD + tid];
  __syncthreads();
  float4* b4 = (float4*)(out + ((size_t)t * NN + blockIdx.x * 800) * CD);
  for (int i = tid; i < 6400; i += 256) {
    float4 v = b4[i];
    int c0 = (4 * i) & 31;
    v.x = __expf(v.x) * inv[c0];
    v.y = __expf(v.y) * inv[c0 + 1];
    v.z = __expf(v.z) * inv[c0 + 2];
    v.w = __expf(v.w) * inv[c0 + 3];
    b4[i] = v;
  }
}

// ---------------- launch ----------------

extern "C" void kernel_launch(void* const* d_in, const int* in_sizes, int n_in,
                              void* d_out, int out_size, void* d_ws, size_t ws_size,
                              hipStream_t stream) {
  const float* x   = (const float*)d_in[0];
  const float* W1  = (const float*)d_in[1];
  const float* as1 = (const float*)d_in[2];
  const float* ad1 = (const float*)d_in[3];
  const float* b1  = (const float*)d_in[4];
  const float* W2  = (const float*)d_in[5];
  const float* as2 = (const float*)d_in[6];
  const float* ad2 = (const float*)d_in[7];
  const float* b2  = (const float*)d_in[8];
  const float* wih = (const float*)d_in[9];
  const float* whh = (const float*)d_in[10];
  const float* bih = (const float*)d_in[11];
  const float* bhh = (const float*)d_in[12];
  const int*   ei  = (const int*)d_in[13];
  const int* srcp = ei;
  const int* dstp = ei + NE;
  float* out = (float*)d_out;

  float* ws = (float*)d_ws;
  float* aggx  = ws;  ws += (size_t)TT * NN * 256;   // 164 MB
  float* den1  = ws;  ws += (size_t)TT * NN * 8;
  float* al1s  = ws;  ws += (size_t)TT * NN * 8;
  float* al1d  = ws;  ws += (size_t)TT * NN * 8;
  float* h2    = ws;  ws += (size_t)TT * NN * CD;
  float* al2s  = ws;  ws += (size_t)TT * NN;
  float* al2d  = ws;  ws += (size_t)TT * NN;
  float* agg2o = ws;  ws += (size_t)TT * NN * CD;
  float* sums  = ws;  ws += TT * CD;
  float* wsrc  = ws;  ws += 256;
  float* wdst  = ws;  ws += 256;
  float* W1T   = ws;  ws += D1 * 32;
  float* W2T   = ws;  ws += 32 * D1;
  int* rowptr = (int*)ws;
  int* fill   = rowptr + NN + 1;
  int* csr    = fill + NN;
  int* deg    = csr + NE;

  hipMemsetAsync(sums, 0, TT * CD * sizeof(float), stream);
  hipMemsetAsync(deg, 0, NN * sizeof(int), stream);

  k_deg<<<(NE + 255) / 256, 256, 0, stream>>>(dstp, deg);
  k_scan<<<1, 1024, 0, stream>>>(deg, rowptr, fill);
  k_fill<<<(NE + 255) / 256, 256, 0, stream>>>(srcp, dstp, fill, csr);
  k_prew<<<1, 256, 0, stream>>>(W1, as1, ad1, W2, wsrc, wdst, W1T, W2T);

  k_logits8<<<(NN / 32) * TT, 256, 0, stream>>>(x, wsrc, wdst, al1s, al1d);
  k_gat1<<<NN / 4, 256, 0, stream>>>(x, al1s, al1d, rowptr, csr, aggx, den1);
  k_post<<<(NN / 8) * TT, 256, 0, stream>>>(aggx, den1, W1T, b1, W2T, as2, ad2,
                                            h2, al2s, al2d);
  k_agg2<<<NN / 4, 256, 0, stream>>>(h2, al2s, al2d, rowptr, csr, b2, agg2o);
  k_lstm_all<<<NN / 16, 256, 0, stream>>>(agg2o, wih, whh, bih, bhh, out);

  k_sm_sum<<<dim3(25, TT), 256, 0, stream>>>(out, sums);
  k_sm_scale<<<dim3(25, TT), 256, 0, stream>>>(out, sums);
}

// Round 2
// 826.822 us; speedup vs baseline: 1.2536x; 1.2536x over previous
//
#include <hip/hip_runtime.h>
#include <math.h>

#define NN 20000   // nodes
#define NE 320000  // edges (without self-loops)
#define TT 8       // timesteps
#define D1 256     // H*F layer-1 width
#define CD 32      // layer-2 width == LSTM hidden

// ---------------- CSR build (once per launch; edges identical across t) ----------------

__global__ __launch_bounds__(256) void k_deg(const int* __restrict__ dst, int* __restrict__ deg) {
  int e = blockIdx.x * 256 + threadIdx.x;
  if (e < NE) atomicAdd(&deg[dst[e]], 1);
}

__global__ __launch_bounds__(1024) void k_scan(const int* __restrict__ deg,
                                               int* __restrict__ rowptr, int* __restrict__ fill) {
  __shared__ int sd[1024];
  __shared__ int carry_s;
  int tid = threadIdx.x;
  if (tid == 0) { carry_s = 0; rowptr[0] = 0; }
  __syncthreads();
  for (int base = 0; base < NN; base += 1024) {
    int i = base + tid;
    int v = (i < NN) ? deg[i] : 0;
    sd[tid] = v;
    __syncthreads();
    for (int off = 1; off < 1024; off <<= 1) {
      int t = (tid >= off) ? sd[tid - off] : 0;
      __syncthreads();
      sd[tid] += t;
      __syncthreads();
    }
    int incl = sd[tid];
    int carry = carry_s;
    if (i < NN) { rowptr[i + 1] = carry + incl; fill[i] = carry + incl - v; }
    __syncthreads();
    if (tid == 1023) carry_s = carry + sd[1023];
    __syncthreads();
  }
}

__global__ __launch_bounds__(256) void k_fill(const int* __restrict__ src, const int* __restrict__ dst,
                                              int* __restrict__ fill, int* __restrict__ csr) {
  int e = blockIdx.x * 256 + threadIdx.x;
  if (e < NE) {
    int pos = atomicAdd(&fill[dst[e]], 1);
    csr[pos] = src[e];
  }
}

// ---------------- one-time: folded attention vectors + weight transposes --------------------

__global__ __launch_bounds__(256) void k_prew(const float* __restrict__ W1,
    const float* __restrict__ as1, const float* __restrict__ ad1,
    const float* __restrict__ W2,
    float* __restrict__ wsrc, float* __restrict__ wdst,
    float* __restrict__ W1T, float* __restrict__ W2T) {
  int tid = threadIdx.x;
  int k = tid >> 3, h = tid & 7;
  float s = 0.f, d = 0.f;
  #pragma unroll
  for (int f = 0; f < 32; ++f) {
    float wv = W1[k * D1 + h * 32 + f];
    s = fmaf(wv, as1[h * 32 + f], s);
    d = fmaf(wv, ad1[h * 32 + f], d);
  }
  wsrc[k * 8 + h] = s;
  wdst[k * 8 + h] = d;
  for (int i = tid; i < D1 * 32; i += 256) {
    int j = i >> 5, kk = i & 31;
    W1T[i] = W1[kk * D1 + j];          // W1T[j*32+kk]
  }
  for (int i = tid; i < 32 * D1; i += 256) {
    int f = i >> 8, kk = i & 255;
    W2T[i] = W2[kk * CD + f];          // W2T[f*256+kk]
  }
}

// ---------------- logits for all t: als/ald = x @ w~ ; t = blockIdx.x & 7 -------------------

__global__ __launch_bounds__(256) void k_logits8(const float* __restrict__ x,
    const float* __restrict__ wsrc, const float* __restrict__ wdst,
    float* __restrict__ als, float* __restrict__ ald) {
  __shared__ float xs[32 * 33];
  __shared__ float wsr[256], wdr[256];
  int tid = threadIdx.x;
  int t = blockIdx.x & 7;
  int n0 = (blockIdx.x >> 3) * 32;
  const float* xt = x + (size_t)t * NN * 32;
  int nl = tid >> 3, h = tid & 7;
  for (int i = tid; i < 1024; i += 256) {
    int g = i >> 5, k = i & 31;
    xs[g * 33 + k] = xt[n0 * 32 + i];
  }
  wsr[tid] = wsrc[tid];
  wdr[tid] = wdst[tid];
  __syncthreads();
  const float* xr = xs + nl * 33;
  float as = 0.f, ad = 0.f;
  #pragma unroll
  for (int k = 0; k < 32; ++k) {
    float xv = xr[k];
    as = fmaf(xv, wsr[k * 8 + h], as);
    ad = fmaf(xv, wdr[k * 8 + h], ad);
  }
  als[(size_t)t * NN * 8 + n0 * 8 + tid] = as;
  ald[(size_t)t * NN * 8 + n0 * 8 + tid] = ad;
}

// ---------------- layer-1 gather, ALL t in one wave: wave=node, lane=(t,h), 2-edge unroll ---

__global__ __launch_bounds__(256, 4) void k_gat1(const float* __restrict__ x,
    const float* __restrict__ als, const float* __restrict__ ald,
    const int* __restrict__ rowptr, const int* __restrict__ csr,
    float* __restrict__ aggx, float* __restrict__ den1) {
  int tid = threadIdx.x;
  int wv = tid >> 6, lane = tid & 63;
  int t = lane >> 3, h = lane & 7;
  int n = blockIdx.x * 4 + wv;
  const float* alst = als + (size_t)t * NN * 8 + h;           // + s*8 per edge
  float adv = ald[(size_t)t * NN * 8 + (size_t)n * 8 + h];
  const float4* x4t = (const float4*)(x + (size_t)t * NN * 32);
  float4 acc[8];
  #pragma unroll
  for (int q = 0; q < 8; ++q) acc[q] = make_float4(0.f, 0.f, 0.f, 0.f);
  float den = 0.f;
  int beg = rowptr[n], end = rowptr[n + 1];
  // virtual list [beg, end]: edges then self-loop at position `end`
  int v = beg;
  for (; v + 1 <= end; v += 2) {
    int s0 = csr[v];                              // v < end guaranteed here
    int s1 = (v + 1 < end) ? csr[v + 1] : n;
    float a0 = alst[(size_t)s0 * 8] + adv;
    float a1 = alst[(size_t)s1 * 8] + adv;
    const float4* xr0 = x4t + (size_t)s0 * 8;
    const float4* xr1 = x4t + (size_t)s1 * 8;
    a0 = fmaxf(a0, 0.2f * a0);
    a1 = fmaxf(a1, 0.2f * a1);
    float e0 = __expf(a0), e1 = __expf(a1);
    float4 u0 = xr0[0], u1 = xr0[1], u2 = xr0[2], u3 = xr0[3];
    float4 u4 = xr0[4], u5 = xr0[5], u6 = xr0[6], u7 = xr0[7];
    float4 w0 = xr1[0], w1 = xr1[1], w2 = xr1[2], w3 = xr1[3];
    float4 w4 = xr1[4], w5 = xr1[5], w6 = xr1[6], w7 = xr1[7];
    acc[0].x = fmaf(e1, w0.x, fmaf(e0, u0.x, acc[0].x));
    acc[0].y = fmaf(e1, w0.y, fmaf(e0, u0.y, acc[0].y));
    acc[0].z = fmaf(e1, w0.z, fmaf(e0, u0.z, acc[0].z));
    acc[0].w = fmaf(e1, w0.w, fmaf(e0, u0.w, acc[0].w));
    acc[1].x = fmaf(e1, w1.x, fmaf(e0, u1.x, acc[1].x));
    acc[1].y = fmaf(e1, w1.y, fmaf(e0, u1.y, acc[1].y));
    acc[1].z = fmaf(e1, w1.z, fmaf(e0, u1.z, acc[1].z));
    acc[1].w = fmaf(e1, w1.w, fmaf(e0, u1.w, acc[1].w));
    acc[2].x = fmaf(e1, w2.x, fmaf(e0, u2.x, acc[2].x));
    acc[2].y = fmaf(e1, w2.y, fmaf(e0, u2.y, acc[2].y));
    acc[2].z = fmaf(e1, w2.z, fmaf(e0, u2.z, acc[2].z));
    acc[2].w = fmaf(e1, w2.w, fmaf(e0, u2.w, acc[2].w));
    acc[3].x = fmaf(e1, w3.x, fmaf(e0, u3.x, acc[3].x));
    acc[3].y = fmaf(e1, w3.y, fmaf(e0, u3.y, acc[3].y));
    acc[3].z = fmaf(e1, w3.z, fmaf(e0, u3.z, acc[3].z));
    acc[3].w = fmaf(e1, w3.w, fmaf(e0, u3.w, acc[3].w));
    acc[4].x = fmaf(e1, w4.x, fmaf(e0, u4.x, acc[4].x));
    acc[4].y = fmaf(e1, w4.y, fmaf(e0, u4.y, acc[4].y));
    acc[4].z = fmaf(e1, w4.z, fmaf(e0, u4.z, acc[4].z));
    acc[4].w = fmaf(e1, w4.w, fmaf(e0, u4.w, acc[4].w));
    acc[5].x = fmaf(e1, w5.x, fmaf(e0, u5.x, acc[5].x));
    acc[5].y = fmaf(e1, w5.y, fmaf(e0, u5.y, acc[5].y));
    acc[5].z = fmaf(e1, w5.z, fmaf(e0, u5.z, acc[5].z));
    acc[5].w = fmaf(e1, w5.w, fmaf(e0, u5.w, acc[5].w));
    acc[6].x = fmaf(e1, w6.x, fmaf(e0, u6.x, acc[6].x));
    acc[6].y = fmaf(e1, w6.y, fmaf(e0, u6.y, acc[6].y));
    acc[6].z = fmaf(e1, w6.z, fmaf(e0, u6.z, acc[6].z));
    acc[6].w = fmaf(e1, w6.w, fmaf(e0, u6.w, acc[6].w));
    acc[7].x = fmaf(e1, w7.x, fmaf(e0, u7.x, acc[7].x));
    acc[7].y = fmaf(e1, w7.y, fmaf(e0, u7.y, acc[7].y));
    acc[7].z = fmaf(e1, w7.z, fmaf(e0, u7.z, acc[7].z));
    acc[7].w = fmaf(e1, w7.w, fmaf(e0, u7.w, acc[7].w));
    den += e0 + e1;
  }
  if (v <= end) {                                 // 1 leftover (edge or self-loop)
    int s = (v < end) ? csr[v] : n;
    float a = alst[(size_t)s * 8] + adv;
    a = fmaxf(a, 0.2f * a);
    float e = __expf(a);
    const float4* xr = x4t + (size_t)s * 8;
    #pragma unroll
    for (int q = 0; q < 8; ++q) {
      float4 xv = xr[q];
      acc[q].x = fmaf(e, xv.x, acc[q].x);
      acc[q].y = fmaf(e, xv.y, acc[q].y);
      acc[q].z = fmaf(e, xv.z, acc[q].z);
      acc[q].w = fmaf(e, xv.w, acc[q].w);
    }
    den += e;
  }
  float4* ao = (float4*)(aggx + ((size_t)t * NN + n) * 256 + h * 32);
  #pragma unroll
  for (int q = 0; q < 8; ++q) ao[q] = acc[q];
  den1[((size_t)t * NN + n) * 8 + h] = den;
}

// ---------------- dense epilogue: 8 nodes/block, 16.9 KB LDS -> 8 blocks/CU ----------------
// launch_bounds(256,6): VGPR cap ~85 so the allocator keeps the ~64-VGPR allocation of the
// round-0 kernel WITHOUT spilling (256,8 forced 32 VGPR -> 1 GB scratch traffic, 3x slower).
// Runtime occupancy is resource-determined: VGPR<=64 + LDS 16.9KB -> 8 blocks/CU (wave cap).

__global__ __launch_bounds__(256, 6) void k_post(const float* __restrict__ aggx,
    const float* __restrict__ den1, const float* __restrict__ W1T, const float* __restrict__ b1,
    const float* __restrict__ W2T, const float* __restrict__ as2, const float* __restrict__ ad2,
    float* __restrict__ h2, float* __restrict__ al2s, float* __restrict__ al2d) {
  __shared__ float aggs[8 * 256];    // phase-2 input; aliased as part[8][8][32] in phase 3
  __shared__ float rels[8 * 256];
  __shared__ float dens[8 * 8];      // INVERSE denominators
  float* part = aggs;                // 8*8*32 == 8*256 floats exactly
  int tid = threadIdx.x;
  int t = blockIdx.x & 7;
  int n0 = (blockIdx.x >> 3) * 8;

  const float4* ag4 = (const float4*)(aggx + ((size_t)t * NN + n0) * 256);
  float4* as4 = (float4*)aggs;
  #pragma unroll
  for (int k = 0; k < 2; ++k) as4[tid + k * 256] = ag4[tid + k * 256];
  if (tid < 64) dens[tid] = 1.f / den1[((size_t)t * NN + n0) * 8 + tid];

  int u = tid & 127, grp = tid >> 7;
  int j0 = 2 * u;
  int hj = j0 >> 5;
  float4 w1a[8], w1b[8];
  const float4* w1p = (const float4*)(W1T + j0 * 32);
  #pragma unroll
  for (int q8 = 0; q8 < 8; ++q8) { w1a[q8] = w1p[q8]; w1b[q8] = w1p[q8 + 8]; }
  float bj0 = b1[j0], bj1 = b1[j0 + 1];
  __syncthreads();

  // phase 2: rows grp*4..+3, columns j0, j0+1 (aggs reads shared by both columns)
  #pragma unroll
  for (int g = 0; g < 4; ++g) {
    int row = grp * 4 + g;
    const float4* ar4 = (const float4*)(aggs + row * 256 + hj * 32);
    float a0 = 0.f, a1 = 0.f;
    #pragma unroll
    for (int k4 = 0; k4 < 8; ++k4) {
      float4 av = ar4[k4];
      a0 = fmaf(av.x, w1a[k4].x, fmaf(av.y, w1a[k4].y,
           fmaf(av.z, w1a[k4].z, fmaf(av.w, w1a[k4].w, a0))));
      a1 = fmaf(av.x, w1b[k4].x, fmaf(av.y, w1b[k4].y,
           fmaf(av.z, w1b[k4].z, fmaf(av.w, w1b[k4].w, a1))));
    }
    float invd = dens[row * 8 + hj];
    float2 r;
    r.x = fmaxf(fmaf(a0, invd, bj0), 0.f);
    r.y = fmaxf(fmaf(a1, invd, bj1), 0.f);
    *(float2*)(rels + row * 256 + j0) = r;
  }
  __syncthreads();   // rels ready; aggs dead -> reuse as part

  // phase 3: q-split over K (8 chunks of 32), columns f0, f0+1
  int q = u >> 4, fp = u & 15, f0 = 2 * fp;
  float4 w2a[8], w2b[8];
  const float4* w2pa = (const float4*)(W2T + f0 * 256 + q * 32);
  const float4* w2pb = (const float4*)(W2T + (f0 + 1) * 256 + q * 32);
  #pragma unroll
  for (int q8 = 0; q8 < 8; ++q8) { w2a[q8] = w2pa[q8]; w2b[q8] = w2pb[q8]; }
  #pragma unroll
  for (int g = 0; g < 4; ++g) {
    int row = grp * 4 + g;
    const float4* r4 = (const float4*)(rels + row * 256 + q * 32);
    float a0 = 0.f, a1 = 0.f;
    #pragma unroll
    for (int jj = 0; jj < 8; ++jj) {
      float4 a4 = r4[jj];
      a0 = fmaf(a4.x, w2a[jj].x, fmaf(a4.y, w2a[jj].y,
           fmaf(a4.z, w2a[jj].z, fmaf(a4.w, w2a[jj].w, a0))));
      a1 = fmaf(a4.x, w2b[jj].x, fmaf(a4.y, w2b[jj].y,
           fmaf(a4.z, w2b[jj].z, fmaf(a4.w, w2b[jj].w, a1))));
    }
    float2 pr; pr.x = a0; pr.y = a1;
    *(float2*)(part + q * 256 + row * 32 + f0) = pr;
  }
  __syncthreads();

  // reduce over q + h2 write + layer-2 logits (single pass: 8 rows x 32 f = 256 threads)
  float as2f = as2[tid & 31], ad2f = ad2[tid & 31];
  int row = tid >> 5;
  int ff = tid & 31;
  float v = 0.f;
  #pragma unroll
  for (int qq = 0; qq < 8; ++qq) v += part[qq * 256 + row * 32 + ff];
  int nn = n0 + row;
  h2[((size_t)t * NN + nn) * CD + ff] = v;
  float vs = v * as2f, vd = v * ad2f;
  #pragma unroll
  for (int m = 1; m < 32; m <<= 1) {
    vs += __shfl_xor(vs, m, 64);
    vd += __shfl_xor(vd, m, 64);
  }
  if (ff == 0) {
    al2s[(size_t)t * NN + nn] = vs;
    al2d[(size_t)t * NN + nn] = vd;
  }
}

// ---------------- layer-2 aggregation, ALL t in one wave: lane=(t, f-quad), 2-edge unroll ---

__global__ __launch_bounds__(256, 8) void k_agg2(const float* __restrict__ h2,
    const float* __restrict__ al2s, const float* __restrict__ al2d,
    const int* __restrict__ rowptr, const int* __restrict__ csr,
    const float* __restrict__ b2, float* __restrict__ out) {
  int tid = threadIdx.x;
  int wv = tid >> 6, lane = tid & 63;
  int t = lane >> 3, p = lane & 7;
  int n = blockIdx.x * 4 + wv;
  const float* alst = al2s + (size_t)t * NN;
  float adv = al2d[(size_t)t * NN + n];
  const float4* h24 = (const float4*)h2 + (size_t)t * NN * 8 + p;
  float4 b4 = ((const float4*)b2)[p];
  float4 acc = make_float4(0.f, 0.f, 0.f, 0.f);
  float den = 0.f;
  int beg = rowptr[n], end = rowptr[n + 1];
  int v = beg;
  for (; v + 1 <= end; v += 2) {
    int s0 = csr[v];
    int s1 = (v + 1 < end) ? csr[v + 1] : n;
    float a0 = alst[s0] + adv;
    float a1 = alst[s1] + adv;
    float4 u = h24[(size_t)s0 * 8];
    float4 w = h24[(size_t)s1 * 8];
    a0 = fmaxf(a0, 0.2f * a0);
    a1 = fmaxf(a1, 0.2f * a1);
    float e0 = __expf(a0), e1 = __expf(a1);
    acc.x = fmaf(e1, w.x, fmaf(e0, u.x, acc.x));
    acc.y = fmaf(e1, w.y, fmaf(e0, u.y, acc.y));
    acc.z = fmaf(e1, w.z, fmaf(e0, u.z, acc.z));
    acc.w = fmaf(e1, w.w, fmaf(e0, u.w, acc.w));
    den += e0 + e1;
  }
  if (v <= end) {
    int s = (v < end) ? csr[v] : n;
    float a = alst[s] + adv;
    a = fmaxf(a, 0.2f * a);
    float e = __expf(a);
    float4 u = h24[(size_t)s * 8];
    acc.x = fmaf(e, u.x, acc.x);
    acc.y = fmaf(e, u.y, acc.y);
    acc.z = fmaf(e, u.z, acc.z);
    acc.w = fmaf(e, u.w, acc.w);
    den += e;
  }
  float inv = 1.f / den;
  float4 o;
  o.x = fmaf(acc.x, inv, b4.x);
  o.y = fmaf(acc.y, inv, b4.y);
  o.z = fmaf(acc.z, inv, b4.z);
  o.w = fmaf(acc.w, inv, b4.w);
  ((float4*)out)[((size_t)t * NN + n) * 8 + p] = o;
}

// ---------------- LSTM, all t in one kernel: weights in VGPRs, h/c in LDS ------------------

__global__ __launch_bounds__(256) void k_lstm_all(const float* __restrict__ agg2o,
    const float* __restrict__ w_ih, const float* __restrict__ w_hh,
    const float* __restrict__ b_ih, const float* __restrict__ b_hh,
    float* __restrict__ out) {
  __shared__ float xs[16 * 32], hs[16 * 32], cs[16 * 32], pre[16 * 128];
  int tid = threadIdx.x;
  int slot = tid >> 7;
  int r = tid & 127;
  float4 wi[8], wh[8];
  const float4* wi4 = (const float4*)(w_ih + r * 32);
  const float4* wh4 = (const float4*)(w_hh + r * 32);
  #pragma unroll
  for (int q = 0; q < 8; ++q) { wi[q] = wi4[q]; wh[q] = wh4[q]; }
  float bias = b_ih[r] + b_hh[r];
  int base = blockIdx.x * 16;
  for (int i = tid; i < 512; i += 256) { hs[i] = 0.f; cs[i] = 0.f; }
  for (int t = 0; t < TT; ++t) {
    for (int i = tid; i < 512; i += 256) xs[i] = agg2o[(size_t)t * NN * 32 + base * 32 + i];
    __syncthreads();
    #pragma unroll
    for (int g = 0; g < 8; ++g) {
      int nl = slot * 8 + g;
      const float4* xv4 = (const float4*)(xs + nl * 32);
      const float4* hv4 = (const float4*)(hs + nl * 32);
      float acc = bias;
      #pragma unroll
      for (int q = 0; q < 8; ++q) {
        float4 a = xv4[q], b = hv4[q];
        acc = fmaf(a.x, wi[q].x, acc);
        acc = fmaf(a.y, wi[q].y, acc);
        acc = fmaf(a.z, wi[q].z, acc);
        acc = fmaf(a.w, wi[q].w, acc);
        acc = fmaf(b.x, wh[q].x, acc);
        acc = fmaf(b.y, wh[q].y, acc);
        acc = fmaf(b.z, wh[q].z, acc);
        acc = fmaf(b.w, wh[q].w, acc);
      }
      pre[nl * 128 + r] = acc;
    }
    __syncthreads();
    for (int i = tid; i < 512; i += 256) {
      int nl = i >> 5, k = i & 31;
      float ai = pre[nl * 128 + k];
      float af = pre[nl * 128 + 32 + k];
      float ag = pre[nl * 128 + 64 + k];
      float ao = pre[nl * 128 + 96 + k];
      float ii = 1.f / (1.f + __expf(-ai));
      float ff = 1.f / (1.f + __expf(-af));
      float gg = tanhf(ag);
      float oo = 1.f / (1.f + __expf(-ao));
      float cn = fmaf(ff, cs[i], ii * gg);
      float hn = oo * tanhf(cn);
      cs[i] = cn; hs[i] = hn;
      out[(size_t)t * NN * 32 + base * 32 + i] = hn;
    }
  }
}

// ---------------- softmax over nodes, coalesced two-pass ----------------

__global__ __launch_bounds__(256) void k_sm_sum(const float* __restrict__ out, float* __restrict__ sums) {
  int t = blockIdx.y;
  const float4* b4 = (const float4*)(out + ((size_t)t * NN + blockIdx.x * 800) * CD);
  int tid = threadIdx.x;
  float4 s4 = make_float4(0.f, 0.f, 0.f, 0.f);
  for (int i = tid; i < 6400; i += 256) {
    float4 v = b4[i];
    s4.x += __expf(v.x); s4.y += __expf(v.y);
    s4.z += __expf(v.z); s4.w += __expf(v.w);
  }
  __shared__ float4 red[256];
  red[tid] = s4;
  __syncthreads();
  for (int off = 128; off >= 8; off >>= 1) {
    if (tid < off) {
      float4 o = red[tid + off];
      red[tid].x += o.x; red[tid].y += o.y; red[tid].z += o.z; red[tid].w += o.w;
    }
    __syncthreads();
  }
  if (tid < 8) {
    float4 v = red[tid];
    int c0 = tid * 4;
    atomicAdd(&sums[t * CD + c0 + 0], v.x);
    atomicAdd(&sums[t * CD + c0 + 1], v.y);
    atomicAdd(&sums[t * CD + c0 + 2], v.z);
    atomicAdd(&sums[t * CD + c0 + 3], v.w);
  }
}

__global__ __launch_bounds__(256) void k_sm_scale(float* __restrict__ out, const float* __restrict__ sums) {
  int t = blockIdx.y;
  __shared__ float inv[CD];
  int tid = threadIdx.x;
  if (tid < CD) inv[tid] = 1.f / sums[t * CD + tid];
  __syncthreads();
  float4* b4 = (float4*)(out + ((size_t)t * NN + blockIdx.x * 800) * CD);
  for (int i = tid; i < 6400; i += 256) {
    float4 v = b4[i];
    int c0 = (4 * i) & 31;
    v.x = __expf(v.x) * inv[c0];
    v.y = __expf(v.y) * inv[c0 + 1];
    v.z = __expf(v.z) * inv[c0 + 2];
    v.w = __expf(v.w) * inv[c0 + 3];
    b4[i] = v;
  }
}

// ---------------- launch ----------------

extern "C" void kernel_launch(void* const* d_in, const int* in_sizes, int n_in,
                              void* d_out, int out_size, void* d_ws, size_t ws_size,
                              hipStream_t stream) {
  const float* x   = (const float*)d_in[0];
  const float* W1  = (const float*)d_in[1];
  const float* as1 = (const float*)d_in[2];
  const float* ad1 = (const float*)d_in[3];
  const float* b1  = (const float*)d_in[4];
  const float* W2  = (const float*)d_in[5];
  const float* as2 = (const float*)d_in[6];
  const float* ad2 = (const float*)d_in[7];
  const float* b2  = (const float*)d_in[8];
  const float* wih = (const float*)d_in[9];
  const float* whh = (const float*)d_in[10];
  const float* bih = (const float*)d_in[11];
  const float* bhh = (const float*)d_in[12];
  const int*   ei  = (const int*)d_in[13];
  const int* srcp = ei;
  const int* dstp = ei + NE;
  float* out = (float*)d_out;

  float* ws = (float*)d_ws;
  float* aggx  = ws;  ws += (size_t)TT * NN * 256;   // 164 MB
  float* den1  = ws;  ws += (size_t)TT * NN * 8;
  float* al1s  = ws;  ws += (size_t)TT * NN * 8;
  float* al1d  = ws;  ws += (size_t)TT * NN * 8;
  float* h2    = ws;  ws += (size_t)TT * NN * CD;
  float* al2s  = ws;  ws += (size_t)TT * NN;
  float* al2d  = ws;  ws += (size_t)TT * NN;
  float* agg2o = ws;  ws += (size_t)TT * NN * CD;
  float* sums  = ws;  ws += TT * CD;
  float* wsrc  = ws;  ws += 256;
  float* wdst  = ws;  ws += 256;
  float* W1T   = ws;  ws += D1 * 32;
  float* W2T   = ws;  ws += 32 * D1;
  int* rowptr = (int*)ws;
  int* fill   = rowptr + NN + 1;
  int* csr    = fill + NN;
  int* deg    = csr + NE;

  hipMemsetAsync(sums, 0, TT * CD * sizeof(float), stream);
  hipMemsetAsync(deg, 0, NN * sizeof(int), stream);

  k_deg<<<(NE + 255) / 256, 256, 0, stream>>>(dstp, deg);
  k_scan<<<1, 1024, 0, stream>>>(deg, rowptr, fill);
  k_fill<<<(NE + 255) / 256, 256, 0, stream>>>(srcp, dstp, fill, csr);
  k_prew<<<1, 256, 0, stream>>>(W1, as1, ad1, W2, wsrc, wdst, W1T, W2T);

  k_logits8<<<(NN / 32) * TT, 256, 0, stream>>>(x, wsrc, wdst, al1s, al1d);
  k_gat1<<<NN / 4, 256, 0, stream>>>(x, al1s, al1d, rowptr, csr, aggx, den1);
  k_post<<<(NN / 8) * TT, 256, 0, stream>>>(aggx, den1, W1T, b1, W2T, as2, ad2,
                                            h2, al2s, al2d);
  k_agg2<<<NN / 4, 256, 0, stream>>>(h2, al2s, al2d, rowptr, csr, b2, agg2o);
  k_lstm_all<<<NN / 16, 256, 0, stream>>>(agg2o, wih, whh, bih, bhh, out);

  k_sm_sum<<<dim3(25, TT), 256, 0, stream>>>(out, sums);
  k_sm_scale<<<dim3(25, TT), 256, 0, stream>>>(out, sums);
}

// Round 3
// 777.003 us; speedup vs baseline: 1.3340x; 1.0641x over previous
//
#include <hip/hip_runtime.h>
#include <math.h>

#define NN 20000   // nodes
#define NE 320000  // edges (without self-loops)
#define TT 8       // timesteps
#define D1 256     // H*F layer-1 width
#define CD 32      // layer-2 width == LSTM hidden

// ---------------- CSR build (once per launch; edges identical across t) ----------------

__global__ __launch_bounds__(256) void k_deg(const int* __restrict__ dst, int* __restrict__ deg) {
  int e = blockIdx.x * 256 + threadIdx.x;
  if (e < NE) atomicAdd(&deg[dst[e]], 1);
}

__global__ __launch_bounds__(1024) void k_scan(const int* __restrict__ deg,
                                               int* __restrict__ rowptr, int* __restrict__ fill) {
  __shared__ int sd[1024];
  __shared__ int carry_s;
  int tid = threadIdx.x;
  if (tid == 0) { carry_s = 0; rowptr[0] = 0; }
  __syncthreads();
  for (int base = 0; base < NN; base += 1024) {
    int i = base + tid;
    int v = (i < NN) ? deg[i] : 0;
    sd[tid] = v;
    __syncthreads();
    for (int off = 1; off < 1024; off <<= 1) {
      int t = (tid >= off) ? sd[tid - off] : 0;
      __syncthreads();
      sd[tid] += t;
      __syncthreads();
    }
    int incl = sd[tid];
    int carry = carry_s;
    if (i < NN) { rowptr[i + 1] = carry + incl; fill[i] = carry + incl - v; }
    __syncthreads();
    if (tid == 1023) carry_s = carry + sd[1023];
    __syncthreads();
  }
}

__global__ __launch_bounds__(256) void k_fill(const int* __restrict__ src, const int* __restrict__ dst,
                                              int* __restrict__ fill, int* __restrict__ csr) {
  int e = blockIdx.x * 256 + threadIdx.x;
  if (e < NE) {
    int pos = atomicAdd(&fill[dst[e]], 1);
    csr[pos] = src[e];
  }
}

// ---------------- one-time: folded attention vectors + weight transposes --------------------

__global__ __launch_bounds__(256) void k_prew(const float* __restrict__ W1,
    const float* __restrict__ as1, const float* __restrict__ ad1,
    const float* __restrict__ W2,
    float* __restrict__ wsrc, float* __restrict__ wdst,
    float* __restrict__ W1T, float* __restrict__ W2T) {
  int tid = threadIdx.x;
  int k = tid >> 3, h = tid & 7;
  float s = 0.f, d = 0.f;
  #pragma unroll
  for (int f = 0; f < 32; ++f) {
    float wv = W1[k * D1 + h * 32 + f];
    s = fmaf(wv, as1[h * 32 + f], s);
    d = fmaf(wv, ad1[h * 32 + f], d);
  }
  wsrc[k * 8 + h] = s;
  wdst[k * 8 + h] = d;
  for (int i = tid; i < D1 * 32; i += 256) {
    int j = i >> 5, kk = i & 31;
    W1T[i] = W1[kk * D1 + j];          // W1T[j*32+kk]
  }
  for (int i = tid; i < 32 * D1; i += 256) {
    int f = i >> 8, kk = i & 255;
    W2T[i] = W2[kk * CD + f];          // W2T[f*256+kk]
  }
}

// ---------------- logits for all t: als/ald = x @ w~ ; t = blockIdx.x & 7 -------------------

__global__ __launch_bounds__(256) void k_logits8(const float* __restrict__ x,
    const float* __restrict__ wsrc, const float* __restrict__ wdst,
    float* __restrict__ als, float* __restrict__ ald) {
  __shared__ float xs[32 * 33];
  __shared__ float wsr[256], wdr[256];
  int tid = threadIdx.x;
  int t = blockIdx.x & 7;
  int n0 = (blockIdx.x >> 3) * 32;
  const float* xt = x + (size_t)t * NN * 32;
  int nl = tid >> 3, h = tid & 7;
  for (int i = tid; i < 1024; i += 256) {
    int g = i >> 5, k = i & 31;
    xs[g * 33 + k] = xt[n0 * 32 + i];
  }
  wsr[tid] = wsrc[tid];
  wdr[tid] = wdst[tid];
  __syncthreads();
  const float* xr = xs + nl * 33;
  float as = 0.f, ad = 0.f;
  #pragma unroll
  for (int k = 0; k < 32; ++k) {
    float xv = xr[k];
    as = fmaf(xv, wsr[k * 8 + h], as);
    ad = fmaf(xv, wdr[k * 8 + h], ad);
  }
  als[(size_t)t * NN * 8 + n0 * 8 + tid] = as;
  ald[(size_t)t * NN * 8 + n0 * 8 + tid] = ad;
}

// ---------------- layer-1 gather, ALL t in one wave: wave=node, lane=(t,h), 2-edge unroll ---

__global__ __launch_bounds__(256, 4) void k_gat1(const float* __restrict__ x,
    const float* __restrict__ als, const float* __restrict__ ald,
    const int* __restrict__ rowptr, const int* __restrict__ csr,
    float* __restrict__ aggx, float* __restrict__ den1) {
  int tid = threadIdx.x;
  int wv = tid >> 6, lane = tid & 63;
  int t = lane >> 3, h = lane & 7;
  int n = blockIdx.x * 4 + wv;
  const float* alst = als + (size_t)t * NN * 8 + h;           // + s*8 per edge
  float adv = ald[(size_t)t * NN * 8 + (size_t)n * 8 + h];
  const float4* x4t = (const float4*)(x + (size_t)t * NN * 32);
  float4 acc[8];
  #pragma unroll
  for (int q = 0; q < 8; ++q) acc[q] = make_float4(0.f, 0.f, 0.f, 0.f);
  float den = 0.f;
  int beg = rowptr[n], end = rowptr[n + 1];
  // virtual list [beg, end]: edges then self-loop at position `end`
  int v = beg;
  for (; v + 1 <= end; v += 2) {
    int s0 = csr[v];                              // v < end guaranteed here
    int s1 = (v + 1 < end) ? csr[v + 1] : n;
    float a0 = alst[(size_t)s0 * 8] + adv;
    float a1 = alst[(size_t)s1 * 8] + adv;
    const float4* xr0 = x4t + (size_t)s0 * 8;
    const float4* xr1 = x4t + (size_t)s1 * 8;
    a0 = fmaxf(a0, 0.2f * a0);
    a1 = fmaxf(a1, 0.2f * a1);
    float e0 = __expf(a0), e1 = __expf(a1);
    float4 u0 = xr0[0], u1 = xr0[1], u2 = xr0[2], u3 = xr0[3];
    float4 u4 = xr0[4], u5 = xr0[5], u6 = xr0[6], u7 = xr0[7];
    float4 w0 = xr1[0], w1 = xr1[1], w2 = xr1[2], w3 = xr1[3];
    float4 w4 = xr1[4], w5 = xr1[5], w6 = xr1[6], w7 = xr1[7];
    acc[0].x = fmaf(e1, w0.x, fmaf(e0, u0.x, acc[0].x));
    acc[0].y = fmaf(e1, w0.y, fmaf(e0, u0.y, acc[0].y));
    acc[0].z = fmaf(e1, w0.z, fmaf(e0, u0.z, acc[0].z));
    acc[0].w = fmaf(e1, w0.w, fmaf(e0, u0.w, acc[0].w));
    acc[1].x = fmaf(e1, w1.x, fmaf(e0, u1.x, acc[1].x));
    acc[1].y = fmaf(e1, w1.y, fmaf(e0, u1.y, acc[1].y));
    acc[1].z = fmaf(e1, w1.z, fmaf(e0, u1.z, acc[1].z));
    acc[1].w = fmaf(e1, w1.w, fmaf(e0, u1.w, acc[1].w));
    acc[2].x = fmaf(e1, w2.x, fmaf(e0, u2.x, acc[2].x));
    acc[2].y = fmaf(e1, w2.y, fmaf(e0, u2.y, acc[2].y));
    acc[2].z = fmaf(e1, w2.z, fmaf(e0, u2.z, acc[2].z));
    acc[2].w = fmaf(e1, w2.w, fmaf(e0, u2.w, acc[2].w));
    acc[3].x = fmaf(e1, w3.x, fmaf(e0, u3.x, acc[3].x));
    acc[3].y = fmaf(e1, w3.y, fmaf(e0, u3.y, acc[3].y));
    acc[3].z = fmaf(e1, w3.z, fmaf(e0, u3.z, acc[3].z));
    acc[3].w = fmaf(e1, w3.w, fmaf(e0, u3.w, acc[3].w));
    acc[4].x = fmaf(e1, w4.x, fmaf(e0, u4.x, acc[4].x));
    acc[4].y = fmaf(e1, w4.y, fmaf(e0, u4.y, acc[4].y));
    acc[4].z = fmaf(e1, w4.z, fmaf(e0, u4.z, acc[4].z));
    acc[4].w = fmaf(e1, w4.w, fmaf(e0, u4.w, acc[4].w));
    acc[5].x = fmaf(e1, w5.x, fmaf(e0, u5.x, acc[5].x));
    acc[5].y = fmaf(e1, w5.y, fmaf(e0, u5.y, acc[5].y));
    acc[5].z = fmaf(e1, w5.z, fmaf(e0, u5.z, acc[5].z));
    acc[5].w = fmaf(e1, w5.w, fmaf(e0, u5.w, acc[5].w));
    acc[6].x = fmaf(e1, w6.x, fmaf(e0, u6.x, acc[6].x));
    acc[6].y = fmaf(e1, w6.y, fmaf(e0, u6.y, acc[6].y));
    acc[6].z = fmaf(e1, w6.z, fmaf(e0, u6.z, acc[6].z));
    acc[6].w = fmaf(e1, w6.w, fmaf(e0, u6.w, acc[6].w));
    acc[7].x = fmaf(e1, w7.x, fmaf(e0, u7.x, acc[7].x));
    acc[7].y = fmaf(e1, w7.y, fmaf(e0, u7.y, acc[7].y));
    acc[7].z = fmaf(e1, w7.z, fmaf(e0, u7.z, acc[7].z));
    acc[7].w = fmaf(e1, w7.w, fmaf(e0, u7.w, acc[7].w));
    den += e0 + e1;
  }
  if (v <= end) {                                 // 1 leftover (edge or self-loop)
    int s = (v < end) ? csr[v] : n;
    float a = alst[(size_t)s * 8] + adv;
    a = fmaxf(a, 0.2f * a);
    float e = __expf(a);
    const float4* xr = x4t + (size_t)s * 8;
    #pragma unroll
    for (int q = 0; q < 8; ++q) {
      float4 xv = xr[q];
      acc[q].x = fmaf(e, xv.x, acc[q].x);
      acc[q].y = fmaf(e, xv.y, acc[q].y);
      acc[q].z = fmaf(e, xv.z, acc[q].z);
      acc[q].w = fmaf(e, xv.w, acc[q].w);
    }
    den += e;
  }
  float4* ao = (float4*)(aggx + ((size_t)t * NN + n) * 256 + h * 32);
  #pragma unroll
  for (int q = 0; q < 8; ++q) ao[q] = acc[q];
  den1[((size_t)t * NN + n) * 8 + h] = den;
}

// ---------------- dense epilogue: 8 nodes/block, 16.9 KB LDS -> 8 blocks/CU ----------------
// launch_bounds(256,4): this compiler maps the 2nd arg to a VGPR cap of ~256/N, so N=4 gives
// cap 64 == the 8-waves/SIMD HW boundary. N=8 forced 32 VGPR (1 GB spill), N=6 forced 40
// (0.4 GB spill). Round-0 (N=4, 16-node) compiled spill-free at exactly 64 VGPR.
// Runtime occupancy is resource-determined: VGPR 64 + 16.9 KB LDS -> 8 blocks/CU (wave cap).

__global__ __launch_bounds__(256, 4) void k_post(const float* __restrict__ aggx,
    const float* __restrict__ den1, const float* __restrict__ W1T, const float* __restrict__ b1,
    const float* __restrict__ W2T, const float* __restrict__ as2, const float* __restrict__ ad2,
    float* __restrict__ h2, float* __restrict__ al2s, float* __restrict__ al2d) {
  __shared__ float aggs[8 * 256];    // phase-2 input; aliased as part[8][8][32] in phase 3
  __shared__ float rels[8 * 256];
  __shared__ float dens[8 * 8];      // INVERSE denominators
  float* part = aggs;                // 8*8*32 == 8*256 floats exactly
  int tid = threadIdx.x;
  int t = blockIdx.x & 7;
  int n0 = (blockIdx.x >> 3) * 8;

  const float4* ag4 = (const float4*)(aggx + ((size_t)t * NN + n0) * 256);
  float4* as4 = (float4*)aggs;
  #pragma unroll
  for (int k = 0; k < 2; ++k) as4[tid + k * 256] = ag4[tid + k * 256];
  if (tid < 64) dens[tid] = 1.f / den1[((size_t)t * NN + n0) * 8 + tid];

  int u = tid & 127, grp = tid >> 7;
  int j0 = 2 * u;
  int hj = j0 >> 5;
  float4 w1a[8], w1b[8];
  const float4* w1p = (const float4*)(W1T + j0 * 32);
  #pragma unroll
  for (int q8 = 0; q8 < 8; ++q8) { w1a[q8] = w1p[q8]; w1b[q8] = w1p[q8 + 8]; }
  float bj0 = b1[j0], bj1 = b1[j0 + 1];
  __syncthreads();

  // phase 2: rows grp*4..+3, columns j0, j0+1 (aggs reads shared by both columns)
  #pragma unroll
  for (int g = 0; g < 4; ++g) {
    int row = grp * 4 + g;
    const float4* ar4 = (const float4*)(aggs + row * 256 + hj * 32);
    float a0 = 0.f, a1 = 0.f;
    #pragma unroll
    for (int k4 = 0; k4 < 8; ++k4) {
      float4 av = ar4[k4];
      a0 = fmaf(av.x, w1a[k4].x, fmaf(av.y, w1a[k4].y,
           fmaf(av.z, w1a[k4].z, fmaf(av.w, w1a[k4].w, a0))));
      a1 = fmaf(av.x, w1b[k4].x, fmaf(av.y, w1b[k4].y,
           fmaf(av.z, w1b[k4].z, fmaf(av.w, w1b[k4].w, a1))));
    }
    float invd = dens[row * 8 + hj];
    float2 r;
    r.x = fmaxf(fmaf(a0, invd, bj0), 0.f);
    r.y = fmaxf(fmaf(a1, invd, bj1), 0.f);
    *(float2*)(rels + row * 256 + j0) = r;
  }
  __syncthreads();   // rels ready; aggs dead -> reuse as part

  // phase 3: q-split over K (8 chunks of 32), columns f0, f0+1
  int q = u >> 4, fp = u & 15, f0 = 2 * fp;
  float4 w2a[8], w2b[8];
  const float4* w2pa = (const float4*)(W2T + f0 * 256 + q * 32);
  const float4* w2pb = (const float4*)(W2T + (f0 + 1) * 256 + q * 32);
  #pragma unroll
  for (int q8 = 0; q8 < 8; ++q8) { w2a[q8] = w2pa[q8]; w2b[q8] = w2pb[q8]; }
  #pragma unroll
  for (int g = 0; g < 4; ++g) {
    int row = grp * 4 + g;
    const float4* r4 = (const float4*)(rels + row * 256 + q * 32);
    float a0 = 0.f, a1 = 0.f;
    #pragma unroll
    for (int jj = 0; jj < 8; ++jj) {
      float4 a4 = r4[jj];
      a0 = fmaf(a4.x, w2a[jj].x, fmaf(a4.y, w2a[jj].y,
           fmaf(a4.z, w2a[jj].z, fmaf(a4.w, w2a[jj].w, a0))));
      a1 = fmaf(a4.x, w2b[jj].x, fmaf(a4.y, w2b[jj].y,
           fmaf(a4.z, w2b[jj].z, fmaf(a4.w, w2b[jj].w, a1))));
    }
    float2 pr; pr.x = a0; pr.y = a1;
    *(float2*)(part + q * 256 + row * 32 + f0) = pr;
  }
  __syncthreads();

  // reduce over q + h2 write + layer-2 logits (single pass: 8 rows x 32 f = 256 threads)
  float as2f = as2[tid & 31], ad2f = ad2[tid & 31];
  int row = tid >> 5;
  int ff = tid & 31;
  float v = 0.f;
  #pragma unroll
  for (int qq = 0; qq < 8; ++qq) v += part[qq * 256 + row * 32 + ff];
  int nn = n0 + row;
  h2[((size_t)t * NN + nn) * CD + ff] = v;
  float vs = v * as2f, vd = v * ad2f;
  #pragma unroll
  for (int m = 1; m < 32; m <<= 1) {
    vs += __shfl_xor(vs, m, 64);
    vd += __shfl_xor(vd, m, 64);
  }
  if (ff == 0) {
    al2s[(size_t)t * NN + nn] = vs;
    al2d[(size_t)t * NN + nn] = vd;
  }
}

// ---------------- layer-2 aggregation, ALL t in one wave: lane=(t, f-quad), 2-edge unroll ---

__global__ __launch_bounds__(256, 8) void k_agg2(const float* __restrict__ h2,
    const float* __restrict__ al2s, const float* __restrict__ al2d,
    const int* __restrict__ rowptr, const int* __restrict__ csr,
    const float* __restrict__ b2, float* __restrict__ out) {
  int tid = threadIdx.x;
  int wv = tid >> 6, lane = tid & 63;
  int t = lane >> 3, p = lane & 7;
  int n = blockIdx.x * 4 + wv;
  const float* alst = al2s + (size_t)t * NN;
  float adv = al2d[(size_t)t * NN + n];
  const float4* h24 = (const float4*)h2 + (size_t)t * NN * 8 + p;
  float4 b4 = ((const float4*)b2)[p];
  float4 acc = make_float4(0.f, 0.f, 0.f, 0.f);
  float den = 0.f;
  int beg = rowptr[n], end = rowptr[n + 1];
  int v = beg;
  for (; v + 1 <= end; v += 2) {
    int s0 = csr[v];
    int s1 = (v + 1 < end) ? csr[v + 1] : n;
    float a0 = alst[s0] + adv;
    float a1 = alst[s1] + adv;
    float4 u = h24[(size_t)s0 * 8];
    float4 w = h24[(size_t)s1 * 8];
    a0 = fmaxf(a0, 0.2f * a0);
    a1 = fmaxf(a1, 0.2f * a1);
    float e0 = __expf(a0), e1 = __expf(a1);
    acc.x = fmaf(e1, w.x, fmaf(e0, u.x, acc.x));
    acc.y = fmaf(e1, w.y, fmaf(e0, u.y, acc.y));
    acc.z = fmaf(e1, w.z, fmaf(e0, u.z, acc.z));
    acc.w = fmaf(e1, w.w, fmaf(e0, u.w, acc.w));
    den += e0 + e1;
  }
  if (v <= end) {
    int s = (v < end) ? csr[v] : n;
    float a = alst[s] + adv;
    a = fmaxf(a, 0.2f * a);
    float e = __expf(a);
    float4 u = h24[(size_t)s * 8];
    acc.x = fmaf(e, u.x, acc.x);
    acc.y = fmaf(e, u.y, acc.y);
    acc.z = fmaf(e, u.z, acc.z);
    acc.w = fmaf(e, u.w, acc.w);
    den += e;
  }
  float inv = 1.f / den;
  float4 o;
  o.x = fmaf(acc.x, inv, b4.x);
  o.y = fmaf(acc.y, inv, b4.y);
  o.z = fmaf(acc.z, inv, b4.z);
  o.w = fmaf(acc.w, inv, b4.w);
  ((float4*)out)[((size_t)t * NN + n) * 8 + p] = o;
}

// ---------------- LSTM, all t in one kernel: weights in VGPRs, h/c in LDS ------------------

__global__ __launch_bounds__(256) void k_lstm_all(const float* __restrict__ agg2o,
    const float* __restrict__ w_ih, const float* __restrict__ w_hh,
    const float* __restrict__ b_ih, const float* __restrict__ b_hh,
    float* __restrict__ out) {
  __shared__ float xs[16 * 32], hs[16 * 32], cs[16 * 32], pre[16 * 128];
  int tid = threadIdx.x;
  int slot = tid >> 7;
  int r = tid & 127;
  float4 wi[8], wh[8];
  const float4* wi4 = (const float4*)(w_ih + r * 32);
  const float4* wh4 = (const float4*)(w_hh + r * 32);
  #pragma unroll
  for (int q = 0; q < 8; ++q) { wi[q] = wi4[q]; wh[q] = wh4[q]; }
  float bias = b_ih[r] + b_hh[r];
  int base = blockIdx.x * 16;
  for (int i = tid; i < 512; i += 256) { hs[i] = 0.f; cs[i] = 0.f; }
  for (int t = 0; t < TT; ++t) {
    for (int i = tid; i < 512; i += 256) xs[i] = agg2o[(size_t)t * NN * 32 + base * 32 + i];
    __syncthreads();
    #pragma unroll
    for (int g = 0; g < 8; ++g) {
      int nl = slot * 8 + g;
      const float4* xv4 = (const float4*)(xs + nl * 32);
      const float4* hv4 = (const float4*)(hs + nl * 32);
      float acc = bias;
      #pragma unroll
      for (int q = 0; q < 8; ++q) {
        float4 a = xv4[q], b = hv4[q];
        acc = fmaf(a.x, wi[q].x, acc);
        acc = fmaf(a.y, wi[q].y, acc);
        acc = fmaf(a.z, wi[q].z, acc);
        acc = fmaf(a.w, wi[q].w, acc);
        acc = fmaf(b.x, wh[q].x, acc);
        acc = fmaf(b.y, wh[q].y, acc);
        acc = fmaf(b.z, wh[q].z, acc);
        acc = fmaf(b.w, wh[q].w, acc);
      }
      pre[nl * 128 + r] = acc;
    }
    __syncthreads();
    for (int i = tid; i < 512; i += 256) {
      int nl = i >> 5, k = i & 31;
      float ai = pre[nl * 128 + k];
      float af = pre[nl * 128 + 32 + k];
      float ag = pre[nl * 128 + 64 + k];
      float ao = pre[nl * 128 + 96 + k];
      float ii = 1.f / (1.f + __expf(-ai));
      float ff = 1.f / (1.f + __expf(-af));
      float gg = tanhf(ag);
      float oo = 1.f / (1.f + __expf(-ao));
      float cn = fmaf(ff, cs[i], ii * gg);
      float hn = oo * tanhf(cn);
      cs[i] = cn; hs[i] = hn;
      out[(size_t)t * NN * 32 + base * 32 + i] = hn;
    }
  }
}

// ---------------- softmax over nodes, coalesced two-pass ----------------

__global__ __launch_bounds__(256) void k_sm_sum(const float* __restrict__ out, float* __restrict__ sums) {
  int t = blockIdx.y;
  const float4* b4 = (const float4*)(out + ((size_t)t * NN + blockIdx.x * 800) * CD);
  int tid = threadIdx.x;
  float4 s4 = make_float4(0.f, 0.f, 0.f, 0.f);
  for (int i = tid; i < 6400; i += 256) {
    float4 v = b4[i];
    s4.x += __expf(v.x); s4.y += __expf(v.y);
    s4.z += __expf(v.z); s4.w += __expf(v.w);
  }
  __shared__ float4 red[256];
  red[tid] = s4;
  __syncthreads();
  for (int off = 128; off >= 8; off >>= 1) {
    if (tid < off) {
      float4 o = red[tid + off];
      red[tid].x += o.x; red[tid].y += o.y; red[tid].z += o.z; red[tid].w += o.w;
    }
    __syncthreads();
  }
  if (tid < 8) {
    float4 v = red[tid];
    int c0 = tid * 4;
    atomicAdd(&sums[t * CD + c0 + 0], v.x);
    atomicAdd(&sums[t * CD + c0 + 1], v.y);
    atomicAdd(&sums[t * CD + c0 + 2], v.z);
    atomicAdd(&sums[t * CD + c0 + 3], v.w);
  }
}

__global__ __launch_bounds__(256) void k_sm_scale(float* __restrict__ out, const float* __restrict__ sums) {
  int t = blockIdx.y;
  __shared__ float inv[CD];
  int tid = threadIdx.x;
  if (tid < CD) inv[tid] = 1.f / sums[t * CD + tid];
  __syncthreads();
  float4* b4 = (float4*)(out + ((size_t)t * NN + blockIdx.x * 800) * CD);
  for (int i = tid; i < 6400; i += 256) {
    float4 v = b4[i];
    int c0 = (4 * i) & 31;
    v.x = __expf(v.x) * inv[c0];
    v.y = __expf(v.y) * inv[c0 + 1];
    v.z = __expf(v.z) * inv[c0 + 2];
    v.w = __expf(v.w) * inv[c0 + 3];
    b4[i] = v;
  }
}

// ---------------- launch ----------------

extern "C" void kernel_launch(void* const* d_in, const int* in_sizes, int n_in,
                              void* d_out, int out_size, void* d_ws, size_t ws_size,
                              hipStream_t stream) {
  const float* x   = (const float*)d_in[0];
  const float* W1  = (const float*)d_in[1];
  const float* as1 = (const float*)d_in[2];
  const float* ad1 = (const float*)d_in[3];
  const float* b1  = (const float*)d_in[4];
  const float* W2  = (const float*)d_in[5];
  const float* as2 = (const float*)d_in[6];
  const float* ad2 = (const float*)d_in[7];
  const float* b2  = (const float*)d_in[8];
  const float* wih = (const float*)d_in[9];
  const float* whh = (const float*)d_in[10];
  const float* bih = (const float*)d_in[11];
  const float* bhh = (const float*)d_in[12];
  const int*   ei  = (const int*)d_in[13];
  const int* srcp = ei;
  const int* dstp = ei + NE;
  float* out = (float*)d_out;

  float* ws = (float*)d_ws;
  float* aggx  = ws;  ws += (size_t)TT * NN * 256;   // 164 MB
  float* den1  = ws;  ws += (size_t)TT * NN * 8;
  float* al1s  = ws;  ws += (size_t)TT * NN * 8;
  float* al1d  = ws;  ws += (size_t)TT * NN * 8;
  float* h2    = ws;  ws += (size_t)TT * NN * CD;
  float* al2s  = ws;  ws += (size_t)TT * NN;
  float* al2d  = ws;  ws += (size_t)TT * NN;
  float* agg2o = ws;  ws += (size_t)TT * NN * CD;
  float* sums  = ws;  ws += TT * CD;
  float* wsrc  = ws;  ws += 256;
  float* wdst  = ws;  ws += 256;
  float* W1T   = ws;  ws += D1 * 32;
  float* W2T   = ws;  ws += 32 * D1;
  int* rowptr = (int*)ws;
  int* fill   = rowptr + NN + 1;
  int* csr    = fill + NN;
  int* deg    = csr + NE;

  hipMemsetAsync(sums, 0, TT * CD * sizeof(float), stream);
  hipMemsetAsync(deg, 0, NN * sizeof(int), stream);

  k_deg<<<(NE + 255) / 256, 256, 0, stream>>>(dstp, deg);
  k_scan<<<1, 1024, 0, stream>>>(deg, rowptr, fill);
  k_fill<<<(NE + 255) / 256, 256, 0, stream>>>(srcp, dstp, fill, csr);
  k_prew<<<1, 256, 0, stream>>>(W1, as1, ad1, W2, wsrc, wdst, W1T, W2T);

  k_logits8<<<(NN / 32) * TT, 256, 0, stream>>>(x, wsrc, wdst, al1s, al1d);
  k_gat1<<<NN / 4, 256, 0, stream>>>(x, al1s, al1d, rowptr, csr, aggx, den1);
  k_post<<<(NN / 8) * TT, 256, 0, stream>>>(aggx, den1, W1T, b1, W2T, as2, ad2,
                                            h2, al2s, al2d);
  k_agg2<<<NN / 4, 256, 0, stream>>>(h2, al2s, al2d, rowptr, csr, b2, agg2o);
  k_lstm_all<<<NN / 16, 256, 0, stream>>>(agg2o, wih, whh, bih, bhh, out);

  k_sm_sum<<<dim3(25, TT), 256, 0, stream>>>(out, sums);
  k_sm_scale<<<dim3(25, TT), 256, 0, stream>>>(out, sums);
}

// Round 4
// 598.863 us; speedup vs baseline: 1.7308x; 1.2975x over previous
//
#include <hip/hip_runtime.h>
#include <math.h>

#define NN 20000   // nodes
#define NE 320000  // edges (without self-loops)
#define TT 8       // timesteps
#define D1 256     // H*F layer-1 width
#define CD 32      // layer-2 width == LSTM hidden

// ---------------- CSR build (once per launch; edges identical across t) ----------------

__global__ __launch_bounds__(256) void k_deg(const int* __restrict__ dst, int* __restrict__ deg) {
  int e = blockIdx.x * 256 + threadIdx.x;
  if (e < NE) atomicAdd(&deg[dst[e]], 1);
}

__global__ __launch_bounds__(1024) void k_scan(const int* __restrict__ deg,
                                               int* __restrict__ rowptr, int* __restrict__ fill) {
  __shared__ int sd[1024];
  __shared__ int carry_s;
  int tid = threadIdx.x;
  if (tid == 0) { carry_s = 0; rowptr[0] = 0; }
  __syncthreads();
  for (int base = 0; base < NN; base += 1024) {
    int i = base + tid;
    int v = (i < NN) ? deg[i] : 0;
    sd[tid] = v;
    __syncthreads();
    for (int off = 1; off < 1024; off <<= 1) {
      int t = (tid >= off) ? sd[tid - off] : 0;
      __syncthreads();
      sd[tid] += t;
      __syncthreads();
    }
    int incl = sd[tid];
    int carry = carry_s;
    if (i < NN) { rowptr[i + 1] = carry + incl; fill[i] = carry + incl - v; }
    __syncthreads();
    if (tid == 1023) carry_s = carry + sd[1023];
    __syncthreads();
  }
}

__global__ __launch_bounds__(256) void k_fill(const int* __restrict__ src, const int* __restrict__ dst,
                                              int* __restrict__ fill, int* __restrict__ csr) {
  int e = blockIdx.x * 256 + threadIdx.x;
  if (e < NE) {
    int pos = atomicAdd(&fill[dst[e]], 1);
    csr[pos] = src[e];
  }
}

// ---------------- one-time: folded attention vectors + weight transposes --------------------

__global__ __launch_bounds__(256) void k_prew(const float* __restrict__ W1,
    const float* __restrict__ as1, const float* __restrict__ ad1,
    const float* __restrict__ W2,
    float* __restrict__ wsrc, float* __restrict__ wdst,
    float* __restrict__ W1T, float* __restrict__ W2T) {
  int tid = threadIdx.x;
  int k = tid >> 3, h = tid & 7;
  float s = 0.f, d = 0.f;
  #pragma unroll
  for (int f = 0; f < 32; ++f) {
    float wv = W1[k * D1 + h * 32 + f];
    s = fmaf(wv, as1[h * 32 + f], s);
    d = fmaf(wv, ad1[h * 32 + f], d);
  }
  wsrc[k * 8 + h] = s;
  wdst[k * 8 + h] = d;
  for (int i = tid; i < D1 * 32; i += 256) {
    int j = i >> 5, kk = i & 31;
    W1T[i] = W1[kk * D1 + j];          // W1T[j*32+kk]
  }
  for (int i = tid; i < 32 * D1; i += 256) {
    int f = i >> 8, kk = i & 255;
    W2T[i] = W2[kk * CD + f];          // W2T[f*256+kk]
  }
}

// ---------------- logits for all t: als/ald = x @ w~ ; t = blockIdx.x & 7 -------------------

__global__ __launch_bounds__(256) void k_logits8(const float* __restrict__ x,
    const float* __restrict__ wsrc, const float* __restrict__ wdst,
    float* __restrict__ als, float* __restrict__ ald) {
  __shared__ float xs[32 * 33];
  __shared__ float wsr[256], wdr[256];
  int tid = threadIdx.x;
  int t = blockIdx.x & 7;
  int n0 = (blockIdx.x >> 3) * 32;
  const float* xt = x + (size_t)t * NN * 32;
  int nl = tid >> 3, h = tid & 7;
  for (int i = tid; i < 1024; i += 256) {
    int g = i >> 5, k = i & 31;
    xs[g * 33 + k] = xt[n0 * 32 + i];
  }
  wsr[tid] = wsrc[tid];
  wdr[tid] = wdst[tid];
  __syncthreads();
  const float* xr = xs + nl * 33;
  float as = 0.f, ad = 0.f;
  #pragma unroll
  for (int k = 0; k < 32; ++k) {
    float xv = xr[k];
    as = fmaf(xv, wsr[k * 8 + h], as);
    ad = fmaf(xv, wdr[k * 8 + h], ad);
  }
  als[(size_t)t * NN * 8 + n0 * 8 + tid] = as;
  ald[(size_t)t * NN * 8 + n0 * 8 + tid] = ad;
}

// ---------------- layer-1 gather, ALL t in one wave: wave=node, lane=(t,h), 2-edge unroll ---

__global__ __launch_bounds__(256, 4) void k_gat1(const float* __restrict__ x,
    const float* __restrict__ als, const float* __restrict__ ald,
    const int* __restrict__ rowptr, const int* __restrict__ csr,
    float* __restrict__ aggx, float* __restrict__ den1) {
  int tid = threadIdx.x;
  int wv = tid >> 6, lane = tid & 63;
  int t = lane >> 3, h = lane & 7;
  int n = blockIdx.x * 4 + wv;
  const float* alst = als + (size_t)t * NN * 8 + h;           // + s*8 per edge
  float adv = ald[(size_t)t * NN * 8 + (size_t)n * 8 + h];
  const float4* x4t = (const float4*)(x + (size_t)t * NN * 32);
  float4 acc[8];
  #pragma unroll
  for (int q = 0; q < 8; ++q) acc[q] = make_float4(0.f, 0.f, 0.f, 0.f);
  float den = 0.f;
  int beg = rowptr[n], end = rowptr[n + 1];
  // virtual list [beg, end]: edges then self-loop at position `end`
  int v = beg;
  for (; v + 1 <= end; v += 2) {
    int s0 = csr[v];                              // v < end guaranteed here
    int s1 = (v + 1 < end) ? csr[v + 1] : n;
    float a0 = alst[(size_t)s0 * 8] + adv;
    float a1 = alst[(size_t)s1 * 8] + adv;
    const float4* xr0 = x4t + (size_t)s0 * 8;
    const float4* xr1 = x4t + (size_t)s1 * 8;
    a0 = fmaxf(a0, 0.2f * a0);
    a1 = fmaxf(a1, 0.2f * a1);
    float e0 = __expf(a0), e1 = __expf(a1);
    float4 u0 = xr0[0], u1 = xr0[1], u2 = xr0[2], u3 = xr0[3];
    float4 u4 = xr0[4], u5 = xr0[5], u6 = xr0[6], u7 = xr0[7];
    float4 w0 = xr1[0], w1 = xr1[1], w2 = xr1[2], w3 = xr1[3];
    float4 w4 = xr1[4], w5 = xr1[5], w6 = xr1[6], w7 = xr1[7];
    acc[0].x = fmaf(e1, w0.x, fmaf(e0, u0.x, acc[0].x));
    acc[0].y = fmaf(e1, w0.y, fmaf(e0, u0.y, acc[0].y));
    acc[0].z = fmaf(e1, w0.z, fmaf(e0, u0.z, acc[0].z));
    acc[0].w = fmaf(e1, w0.w, fmaf(e0, u0.w, acc[0].w));
    acc[1].x = fmaf(e1, w1.x, fmaf(e0, u1.x, acc[1].x));
    acc[1].y = fmaf(e1, w1.y, fmaf(e0, u1.y, acc[1].y));
    acc[1].z = fmaf(e1, w1.z, fmaf(e0, u1.z, acc[1].z));
    acc[1].w = fmaf(e1, w1.w, fmaf(e0, u1.w, acc[1].w));
    acc[2].x = fmaf(e1, w2.x, fmaf(e0, u2.x, acc[2].x));
    acc[2].y = fmaf(e1, w2.y, fmaf(e0, u2.y, acc[2].y));
    acc[2].z = fmaf(e1, w2.z, fmaf(e0, u2.z, acc[2].z));
    acc[2].w = fmaf(e1, w2.w, fmaf(e0, u2.w, acc[2].w));
    acc[3].x = fmaf(e1, w3.x, fmaf(e0, u3.x, acc[3].x));
    acc[3].y = fmaf(e1, w3.y, fmaf(e0, u3.y, acc[3].y));
    acc[3].z = fmaf(e1, w3.z, fmaf(e0, u3.z, acc[3].z));
    acc[3].w = fmaf(e1, w3.w, fmaf(e0, u3.w, acc[3].w));
    acc[4].x = fmaf(e1, w4.x, fmaf(e0, u4.x, acc[4].x));
    acc[4].y = fmaf(e1, w4.y, fmaf(e0, u4.y, acc[4].y));
    acc[4].z = fmaf(e1, w4.z, fmaf(e0, u4.z, acc[4].z));
    acc[4].w = fmaf(e1, w4.w, fmaf(e0, u4.w, acc[4].w));
    acc[5].x = fmaf(e1, w5.x, fmaf(e0, u5.x, acc[5].x));
    acc[5].y = fmaf(e1, w5.y, fmaf(e0, u5.y, acc[5].y));
    acc[5].z = fmaf(e1, w5.z, fmaf(e0, u5.z, acc[5].z));
    acc[5].w = fmaf(e1, w5.w, fmaf(e0, u5.w, acc[5].w));
    acc[6].x = fmaf(e1, w6.x, fmaf(e0, u6.x, acc[6].x));
    acc[6].y = fmaf(e1, w6.y, fmaf(e0, u6.y, acc[6].y));
    acc[6].z = fmaf(e1, w6.z, fmaf(e0, u6.z, acc[6].z));
    acc[6].w = fmaf(e1, w6.w, fmaf(e0, u6.w, acc[6].w));
    acc[7].x = fmaf(e1, w7.x, fmaf(e0, u7.x, acc[7].x));
    acc[7].y = fmaf(e1, w7.y, fmaf(e0, u7.y, acc[7].y));
    acc[7].z = fmaf(e1, w7.z, fmaf(e0, u7.z, acc[7].z));
    acc[7].w = fmaf(e1, w7.w, fmaf(e0, u7.w, acc[7].w));
    den += e0 + e1;
  }
  if (v <= end) {                                 // 1 leftover (edge or self-loop)
    int s = (v < end) ? csr[v] : n;
    float a = alst[(size_t)s * 8] + adv;
    a = fmaxf(a, 0.2f * a);
    float e = __expf(a);
    const float4* xr = x4t + (size_t)s * 8;
    #pragma unroll
    for (int q = 0; q < 8; ++q) {
      float4 xv = xr[q];
      acc[q].x = fmaf(e, xv.x, acc[q].x);
      acc[q].y = fmaf(e, xv.y, acc[q].y);
      acc[q].z = fmaf(e, xv.z, acc[q].z);
      acc[q].w = fmaf(e, xv.w, acc[q].w);
    }
    den += e;
  }
  float4* ao = (float4*)(aggx + ((size_t)t * NN + n) * 256 + h * 32);
  #pragma unroll
  for (int q = 0; q < 8; ++q) ao[q] = acc[q];
  den1[((size_t)t * NN + n) * 8 + h] = den;
}

// ---------------- dense epilogue: 16-node tiles, 5 tiles/block, weights resident -----------
// r0<->r3 A/B showed per-block fixed cost (weight loads) dominates: 8-node (2x blocks) was
// 1.8x SLOWER than 16-node. And at <=64 VGPR the 32 float4 of "register" weights CANNOT be
// resident -- the compiler re-loads them from L1 inside the g-loops (VALUBusy 22-42%).
// Fix: launch_bounds(256,1) (VGPR cap 256; ~180 used) so weights truly live in registers,
// and a 5-tile loop per block so the one-time weight load amortizes 5x. Grid 2000.
// Expected ~3 blocks/CU (VGPR-bound), LDS 33KB allows 4.

#define PTILES 5

__global__ __launch_bounds__(256, 1) void k_post(const float* __restrict__ aggx,
    const float* __restrict__ den1, const float* __restrict__ W1T, const float* __restrict__ b1,
    const float* __restrict__ W2T, const float* __restrict__ as2, const float* __restrict__ ad2,
    float* __restrict__ h2, float* __restrict__ al2s, float* __restrict__ al2d) {
  __shared__ float aggs[16 * 256];   // phase-2 input; aliased as part[8][16][32] in phase 3
  __shared__ float rels[16 * 256];
  __shared__ float dens[16 * 8];     // INVERSE denominators
  float* part = aggs;                // 8*16*32 == 16*256 floats exactly
  int tid = threadIdx.x;

  int u = tid & 127, grp = tid >> 7;
  int j0 = 2 * u;
  int hj = j0 >> 5;
  // one-time per block: weights + biases into registers (amortized over PTILES tiles)
  float4 w1a[8], w1b[8];
  const float4* w1p = (const float4*)(W1T + j0 * 32);
  #pragma unroll
  for (int q8 = 0; q8 < 8; ++q8) { w1a[q8] = w1p[q8]; w1b[q8] = w1p[q8 + 8]; }
  float bj0 = b1[j0], bj1 = b1[j0 + 1];
  int q = u >> 4, fp = u & 15, f0 = 2 * fp;
  float4 w2a[8], w2b[8];
  const float4* w2pa = (const float4*)(W2T + f0 * 256 + q * 32);
  const float4* w2pb = (const float4*)(W2T + (f0 + 1) * 256 + q * 32);
  #pragma unroll
  for (int q8 = 0; q8 < 8; ++q8) { w2a[q8] = w2pa[q8]; w2b[q8] = w2pb[q8]; }
  float as2f = as2[tid & 31], ad2f = ad2[tid & 31];

  for (int it = 0; it < PTILES; ++it) {
    int tile = blockIdx.x * PTILES + it;
    int t = tile & 7;
    int n0 = (tile >> 3) * 16;

    if (it > 0) __syncthreads();     // part/dens reads of prev tile done before overwrite

    const float4* ag4 = (const float4*)(aggx + ((size_t)t * NN + n0) * 256);
    float4* as4 = (float4*)aggs;
    #pragma unroll
    for (int k = 0; k < 4; ++k) as4[tid + k * 256] = ag4[tid + k * 256];
    if (tid < 128) dens[tid] = 1.f / den1[((size_t)t * NN + n0) * 8 + tid];
    __syncthreads();

    // phase 2: rows grp*8..+7, columns j0, j0+1 (aggs reads shared by both columns)
    #pragma unroll
    for (int g = 0; g < 8; ++g) {
      int row = grp * 8 + g;
      const float4* ar4 = (const float4*)(aggs + row * 256 + hj * 32);
      float a0 = 0.f, a1 = 0.f;
      #pragma unroll
      for (int k4 = 0; k4 < 8; ++k4) {
        float4 av = ar4[k4];
        a0 = fmaf(av.x, w1a[k4].x, fmaf(av.y, w1a[k4].y,
             fmaf(av.z, w1a[k4].z, fmaf(av.w, w1a[k4].w, a0))));
        a1 = fmaf(av.x, w1b[k4].x, fmaf(av.y, w1b[k4].y,
             fmaf(av.z, w1b[k4].z, fmaf(av.w, w1b[k4].w, a1))));
      }
      float invd = dens[row * 8 + hj];
      float2 r;
      r.x = fmaxf(fmaf(a0, invd, bj0), 0.f);
      r.y = fmaxf(fmaf(a1, invd, bj1), 0.f);
      *(float2*)(rels + row * 256 + j0) = r;
    }
    __syncthreads();   // rels ready; aggs dead -> reuse as part

    // phase 3: q-split over K (8 chunks of 32), columns f0, f0+1
    #pragma unroll
    for (int g = 0; g < 8; ++g) {
      int row = grp * 8 + g;
      const float4* r4 = (const float4*)(rels + row * 256 + q * 32);
      float a0 = 0.f, a1 = 0.f;
      #pragma unroll
      for (int jj = 0; jj < 8; ++jj) {
        float4 a4 = r4[jj];
        a0 = fmaf(a4.x, w2a[jj].x, fmaf(a4.y, w2a[jj].y,
             fmaf(a4.z, w2a[jj].z, fmaf(a4.w, w2a[jj].w, a0))));
        a1 = fmaf(a4.x, w2b[jj].x, fmaf(a4.y, w2b[jj].y,
             fmaf(a4.z, w2b[jj].z, fmaf(a4.w, w2b[jj].w, a1))));
      }
      float2 pr; pr.x = a0; pr.y = a1;
      *(float2*)(part + q * 512 + row * 32 + f0) = pr;
    }
    __syncthreads();

    // reduce over q + h2 write + layer-2 logits
    #pragma unroll
    for (int rep = 0; rep < 2; ++rep) {
      int row = (tid >> 5) + rep * 8;
      int ff = tid & 31;
      float v = 0.f;
      #pragma unroll
      for (int qq = 0; qq < 8; ++qq) v += part[qq * 512 + row * 32 + ff];
      int nn = n0 + row;
      h2[((size_t)t * NN + nn) * CD + ff] = v;
      float vs = v * as2f, vd = v * ad2f;
      #pragma unroll
      for (int m = 1; m < 32; m <<= 1) {
        vs += __shfl_xor(vs, m, 64);
        vd += __shfl_xor(vd, m, 64);
      }
      if (ff == 0) {
        al2s[(size_t)t * NN + nn] = vs;
        al2d[(size_t)t * NN + nn] = vd;
      }
    }
  }
}

// ---------------- layer-2 aggregation, ALL t in one wave: lane=(t, f-quad), 2-edge unroll ---

__global__ __launch_bounds__(256, 8) void k_agg2(const float* __restrict__ h2,
    const float* __restrict__ al2s, const float* __restrict__ al2d,
    const int* __restrict__ rowptr, const int* __restrict__ csr,
    const float* __restrict__ b2, float* __restrict__ out) {
  int tid = threadIdx.x;
  int wv = tid >> 6, lane = tid & 63;
  int t = lane >> 3, p = lane & 7;
  int n = blockIdx.x * 4 + wv;
  const float* alst = al2s + (size_t)t * NN;
  float adv = al2d[(size_t)t * NN + n];
  const float4* h24 = (const float4*)h2 + (size_t)t * NN * 8 + p;
  float4 b4 = ((const float4*)b2)[p];
  float4 acc = make_float4(0.f, 0.f, 0.f, 0.f);
  float den = 0.f;
  int beg = rowptr[n], end = rowptr[n + 1];
  int v = beg;
  for (; v + 1 <= end; v += 2) {
    int s0 = csr[v];
    int s1 = (v + 1 < end) ? csr[v + 1] : n;
    float a0 = alst[s0] + adv;
    float a1 = alst[s1] + adv;
    float4 u = h24[(size_t)s0 * 8];
    float4 w = h24[(size_t)s1 * 8];
    a0 = fmaxf(a0, 0.2f * a0);
    a1 = fmaxf(a1, 0.2f * a1);
    float e0 = __expf(a0), e1 = __expf(a1);
    acc.x = fmaf(e1, w.x, fmaf(e0, u.x, acc.x));
    acc.y = fmaf(e1, w.y, fmaf(e0, u.y, acc.y));
    acc.z = fmaf(e1, w.z, fmaf(e0, u.z, acc.z));
    acc.w = fmaf(e1, w.w, fmaf(e0, u.w, acc.w));
    den += e0 + e1;
  }
  if (v <= end) {
    int s = (v < end) ? csr[v] : n;
    float a = alst[s] + adv;
    a = fmaxf(a, 0.2f * a);
    float e = __expf(a);
    float4 u = h24[(size_t)s * 8];
    acc.x = fmaf(e, u.x, acc.x);
    acc.y = fmaf(e, u.y, acc.y);
    acc.z = fmaf(e, u.z, acc.z);
    acc.w = fmaf(e, u.w, acc.w);
    den += e;
  }
  float inv = 1.f / den;
  float4 o;
  o.x = fmaf(acc.x, inv, b4.x);
  o.y = fmaf(acc.y, inv, b4.y);
  o.z = fmaf(acc.z, inv, b4.z);
  o.w = fmaf(acc.w, inv, b4.w);
  ((float4*)out)[((size_t)t * NN + n) * 8 + p] = o;
}

// ---------------- LSTM, all t in one kernel: weights in VGPRs, h/c in LDS ------------------

__global__ __launch_bounds__(256) void k_lstm_all(const float* __restrict__ agg2o,
    const float* __restrict__ w_ih, const float* __restrict__ w_hh,
    const float* __restrict__ b_ih, const float* __restrict__ b_hh,
    float* __restrict__ out) {
  __shared__ float xs[16 * 32], hs[16 * 32], cs[16 * 32], pre[16 * 128];
  int tid = threadIdx.x;
  int slot = tid >> 7;
  int r = tid & 127;
  float4 wi[8], wh[8];
  const float4* wi4 = (const float4*)(w_ih + r * 32);
  const float4* wh4 = (const float4*)(w_hh + r * 32);
  #pragma unroll
  for (int q = 0; q < 8; ++q) { wi[q] = wi4[q]; wh[q] = wh4[q]; }
  float bias = b_ih[r] + b_hh[r];
  int base = blockIdx.x * 16;
  for (int i = tid; i < 512; i += 256) { hs[i] = 0.f; cs[i] = 0.f; }
  for (int t = 0; t < TT; ++t) {
    for (int i = tid; i < 512; i += 256) xs[i] = agg2o[(size_t)t * NN * 32 + base * 32 + i];
    __syncthreads();
    #pragma unroll
    for (int g = 0; g < 8; ++g) {
      int nl = slot * 8 + g;
      const float4* xv4 = (const float4*)(xs + nl * 32);
      const float4* hv4 = (const float4*)(hs + nl * 32);
      float acc = bias;
      #pragma unroll
      for (int q = 0; q < 8; ++q) {
        float4 a = xv4[q], b = hv4[q];
        acc = fmaf(a.x, wi[q].x, acc);
        acc = fmaf(a.y, wi[q].y, acc);
        acc = fmaf(a.z, wi[q].z, acc);
        acc = fmaf(a.w, wi[q].w, acc);
        acc = fmaf(b.x, wh[q].x, acc);
        acc = fmaf(b.y, wh[q].y, acc);
        acc = fmaf(b.z, wh[q].z, acc);
        acc = fmaf(b.w, wh[q].w, acc);
      }
      pre[nl * 128 + r] = acc;
    }
    __syncthreads();
    for (int i = tid; i < 512; i += 256) {
      int nl = i >> 5, k = i & 31;
      float ai = pre[nl * 128 + k];
      float af = pre[nl * 128 + 32 + k];
      float ag = pre[nl * 128 + 64 + k];
      float ao = pre[nl * 128 + 96 + k];
      float ii = 1.f / (1.f + __expf(-ai));
      float ff = 1.f / (1.f + __expf(-af));
      float gg = tanhf(ag);
      float oo = 1.f / (1.f + __expf(-ao));
      float cn = fmaf(ff, cs[i], ii * gg);
      float hn = oo * tanhf(cn);
      cs[i] = cn; hs[i] = hn;
      out[(size_t)t * NN * 32 + base * 32 + i] = hn;
    }
  }
}

// ---------------- softmax over nodes, coalesced two-pass ----------------

__global__ __launch_bounds__(256) void k_sm_sum(const float* __restrict__ out, float* __restrict__ sums) {
  int t = blockIdx.y;
  const float4* b4 = (const float4*)(out + ((size_t)t * NN + blockIdx.x * 800) * CD);
  int tid = threadIdx.x;
  float4 s4 = make_float4(0.f, 0.f, 0.f, 0.f);
  for (int i = tid; i < 6400; i += 256) {
    float4 v = b4[i];
    s4.x += __expf(v.x); s4.y += __expf(v.y);
    s4.z += __expf(v.z); s4.w += __expf(v.w);
  }
  __shared__ float4 red[256];
  red[tid] = s4;
  __syncthreads();
  for (int off = 128; off >= 8; off >>= 1) {
    if (tid < off) {
      float4 o = red[tid + off];
      red[tid].x += o.x; red[tid].y += o.y; red[tid].z += o.z; red[tid].w += o.w;
    }
    __syncthreads();
  }
  if (tid < 8) {
    float4 v = red[tid];
    int c0 = tid * 4;
    atomicAdd(&sums[t * CD + c0 + 0], v.x);
    atomicAdd(&sums[t * CD + c0 + 1], v.y);
    atomicAdd(&sums[t * CD + c0 + 2], v.z);
    atomicAdd(&sums[t * CD + c0 + 3], v.w);
  }
}

__global__ __launch_bounds__(256) void k_sm_scale(float* __restrict__ out, const float* __restrict__ sums) {
  int t = blockIdx.y;
  __shared__ float inv[CD];
  int tid = threadIdx.x;
  if (tid < CD) inv[tid] = 1.f / sums[t * CD + tid];
  __syncthreads();
  float4* b4 = (float4*)(out + ((size_t)t * NN + blockIdx.x * 800) * CD);
  for (int i = tid; i < 6400; i += 256) {
    float4 v = b4[i];
    int c0 = (4 * i) & 31;
    v.x = __expf(v.x) * inv[c0];
    v.y = __expf(v.y) * inv[c0 + 1];
    v.z = __expf(v.z) * inv[c0 + 2];
    v.w = __expf(v.w) * inv[c0 + 3];
    b4[i] = v;
  }
}

// ---------------- launch ----------------

extern "C" void kernel_launch(void* const* d_in, const int* in_sizes, int n_in,
                              void* d_out, int out_size, void* d_ws, size_t ws_size,
                              hipStream_t stream) {
  const float* x   = (const float*)d_in[0];
  const float* W1  = (const float*)d_in[1];
  const float* as1 = (const float*)d_in[2];
  const float* ad1 = (const float*)d_in[3];
  const float* b1  = (const float*)d_in[4];
  const float* W2  = (const float*)d_in[5];
  const float* as2 = (const float*)d_in[6];
  const float* ad2 = (const float*)d_in[7];
  const float* b2  = (const float*)d_in[8];
  const float* wih = (const float*)d_in[9];
  const float* whh = (const float*)d_in[10];
  const float* bih = (const float*)d_in[11];
  const float* bhh = (const float*)d_in[12];
  const int*   ei  = (const int*)d_in[13];
  const int* srcp = ei;
  const int* dstp = ei + NE;
  float* out = (float*)d_out;

  float* ws = (float*)d_ws;
  float* aggx  = ws;  ws += (size_t)TT * NN * 256;   // 164 MB
  float* den1  = ws;  ws += (size_t)TT * NN * 8;
  float* al1s  = ws;  ws += (size_t)TT * NN * 8;
  float* al1d  = ws;  ws += (size_t)TT * NN * 8;
  float* h2    = ws;  ws += (size_t)TT * NN * CD;
  float* al2s  = ws;  ws += (size_t)TT * NN;
  float* al2d  = ws;  ws += (size_t)TT * NN;
  float* agg2o = ws;  ws += (size_t)TT * NN * CD;
  float* sums  = ws;  ws += TT * CD;
  float* wsrc  = ws;  ws += 256;
  float* wdst  = ws;  ws += 256;
  float* W1T   = ws;  ws += D1 * 32;
  float* W2T   = ws;  ws += 32 * D1;
  int* rowptr = (int*)ws;
  int* fill   = rowptr + NN + 1;
  int* csr    = fill + NN;
  int* deg    = csr + NE;

  hipMemsetAsync(sums, 0, TT * CD * sizeof(float), stream);
  hipMemsetAsync(deg, 0, NN * sizeof(int), stream);

  k_deg<<<(NE + 255) / 256, 256, 0, stream>>>(dstp, deg);
  k_scan<<<1, 1024, 0, stream>>>(deg, rowptr, fill);
  k_fill<<<(NE + 255) / 256, 256, 0, stream>>>(srcp, dstp, fill, csr);
  k_prew<<<1, 256, 0, stream>>>(W1, as1, ad1, W2, wsrc, wdst, W1T, W2T);

  k_logits8<<<(NN / 32) * TT, 256, 0, stream>>>(x, wsrc, wdst, al1s, al1d);
  k_gat1<<<NN / 4, 256, 0, stream>>>(x, al1s, al1d, rowptr, csr, aggx, den1);
  k_post<<<(NN / 16) * TT / PTILES, 256, 0, stream>>>(aggx, den1, W1T, b1, W2T, as2, ad2,
                                                      h2, al2s, al2d);
  k_agg2<<<NN / 4, 256, 0, stream>>>(h2, al2s, al2d, rowptr, csr, b2, agg2o);
  k_lstm_all<<<NN / 16, 256, 0, stream>>>(agg2o, wih, whh, bih, bhh, out);

  k_sm_sum<<<dim3(25, TT), 256, 0, stream>>>(out, sums);
  k_sm_scale<<<dim3(25, TT), 256, 0, stream>>>(out, sums);
}

// Round 5
// 597.639 us; speedup vs baseline: 1.7343x; 1.0020x over previous
//
#include <hip/hip_runtime.h>
#include <math.h>

#define NN 20000   // nodes
#define NE 320000  // edges (without self-loops)
#define TT 8       // timesteps
#define D1 256     // H*F layer-1 width
#define CD 32      // layer-2 width == LSTM hidden

// ---------------- CSR build (once per launch; edges identical across t) ----------------

__global__ __launch_bounds__(256) void k_deg(const int* __restrict__ dst, int* __restrict__ deg) {
  int e = blockIdx.x * 256 + threadIdx.x;
  if (e < NE) atomicAdd(&deg[dst[e]], 1);
}

__global__ __launch_bounds__(1024) void k_scan(const int* __restrict__ deg,
                                               int* __restrict__ rowptr, int* __restrict__ fill) {
  __shared__ int sd[1024];
  __shared__ int carry_s;
  int tid = threadIdx.x;
  if (tid == 0) { carry_s = 0; rowptr[0] = 0; }
  __syncthreads();
  for (int base = 0; base < NN; base += 1024) {
    int i = base + tid;
    int v = (i < NN) ? deg[i] : 0;
    sd[tid] = v;
    __syncthreads();
    for (int off = 1; off < 1024; off <<= 1) {
      int t = (tid >= off) ? sd[tid - off] : 0;
      __syncthreads();
      sd[tid] += t;
      __syncthreads();
    }
    int incl = sd[tid];
    int carry = carry_s;
    if (i < NN) { rowptr[i + 1] = carry + incl; fill[i] = carry + incl - v; }
    __syncthreads();
    if (tid == 1023) carry_s = carry + sd[1023];
    __syncthreads();
  }
}

__global__ __launch_bounds__(256) void k_fill(const int* __restrict__ src, const int* __restrict__ dst,
                                              int* __restrict__ fill, int* __restrict__ csr) {
  int e = blockIdx.x * 256 + threadIdx.x;
  if (e < NE) {
    int pos = atomicAdd(&fill[dst[e]], 1);
    csr[pos] = src[e];
  }
}

// ---------------- one-time: folded attention vectors + weight transposes --------------------

__global__ __launch_bounds__(256) void k_prew(const float* __restrict__ W1,
    const float* __restrict__ as1, const float* __restrict__ ad1,
    const float* __restrict__ W2,
    float* __restrict__ wsrc, float* __restrict__ wdst,
    float* __restrict__ W1T, float* __restrict__ W2T) {
  int tid = threadIdx.x;
  int k = tid >> 3, h = tid & 7;
  float s = 0.f, d = 0.f;
  #pragma unroll
  for (int f = 0; f < 32; ++f) {
    float wv = W1[k * D1 + h * 32 + f];
    s = fmaf(wv, as1[h * 32 + f], s);
    d = fmaf(wv, ad1[h * 32 + f], d);
  }
  wsrc[k * 8 + h] = s;
  wdst[k * 8 + h] = d;
  for (int i = tid; i < D1 * 32; i += 256) {
    int j = i >> 5, kk = i & 31;
    W1T[i] = W1[kk * D1 + j];          // W1T[j*32+kk]
  }
  for (int i = tid; i < 32 * D1; i += 256) {
    int f = i >> 8, kk = i & 255;
    W2T[i] = W2[kk * CD + f];          // W2T[f*256+kk]
  }
}

// ---------------- logits for all t: als/ald = x @ w~ ; t = blockIdx.x & 7 -------------------

__global__ __launch_bounds__(256) void k_logits8(const float* __restrict__ x,
    const float* __restrict__ wsrc, const float* __restrict__ wdst,
    float* __restrict__ als, float* __restrict__ ald) {
  __shared__ float xs[32 * 33];
  __shared__ float wsr[256], wdr[256];
  int tid = threadIdx.x;
  int t = blockIdx.x & 7;
  int n0 = (blockIdx.x >> 3) * 32;
  const float* xt = x + (size_t)t * NN * 32;
  int nl = tid >> 3, h = tid & 7;
  for (int i = tid; i < 1024; i += 256) {
    int g = i >> 5, k = i & 31;
    xs[g * 33 + k] = xt[n0 * 32 + i];
  }
  wsr[tid] = wsrc[tid];
  wdr[tid] = wdst[tid];
  __syncthreads();
  const float* xr = xs + nl * 33;
  float as = 0.f, ad = 0.f;
  #pragma unroll
  for (int k = 0; k < 32; ++k) {
    float xv = xr[k];
    as = fmaf(xv, wsr[k * 8 + h], as);
    ad = fmaf(xv, wdr[k * 8 + h], ad);
  }
  als[(size_t)t * NN * 8 + n0 * 8 + tid] = as;
  ald[(size_t)t * NN * 8 + n0 * 8 + tid] = ad;
}

// ---------------- layer-1 gather, ALL t in one wave: wave=node, lane=(t,h), 2-edge unroll ---
// launch_bounds(256,2): VGPR cap 128 (this compiler: cap ~ 256/N). The 2-edge staging needs
// 16 float4 (64 VGPR) + 32 acc + addressing ~= 112. Round-4's (256,4) cap of 64 forced the
// compiler to serialize staging (VGPR_Count=48, MLP ~4) -> latency-bound at 13.5% VALU /
// 39% HBM. Cap 128 keeps all 16 loads in flight; HW still allows 4 waves/SIMD at <=128.

__global__ __launch_bounds__(256, 2) void k_gat1(const float* __restrict__ x,
    const float* __restrict__ als, const float* __restrict__ ald,
    const int* __restrict__ rowptr, const int* __restrict__ csr,
    float* __restrict__ aggx, float* __restrict__ den1) {
  int tid = threadIdx.x;
  int wv = tid >> 6, lane = tid & 63;
  int t = lane >> 3, h = lane & 7;
  int n = blockIdx.x * 4 + wv;
  const float* alst = als + (size_t)t * NN * 8 + h;           // + s*8 per edge
  float adv = ald[(size_t)t * NN * 8 + (size_t)n * 8 + h];
  const float4* x4t = (const float4*)(x + (size_t)t * NN * 32);
  float4 acc[8];
  #pragma unroll
  for (int q = 0; q < 8; ++q) acc[q] = make_float4(0.f, 0.f, 0.f, 0.f);
  float den = 0.f;
  int beg = rowptr[n], end = rowptr[n + 1];
  // virtual list [beg, end]: edges then self-loop at position `end`
  int v = beg;
  for (; v + 1 <= end; v += 2) {
    int s0 = csr[v];                              // v < end guaranteed here
    int s1 = (v + 1 < end) ? csr[v + 1] : n;
    float a0 = alst[(size_t)s0 * 8] + adv;
    float a1 = alst[(size_t)s1 * 8] + adv;
    const float4* xr0 = x4t + (size_t)s0 * 8;
    const float4* xr1 = x4t + (size_t)s1 * 8;
    a0 = fmaxf(a0, 0.2f * a0);
    a1 = fmaxf(a1, 0.2f * a1);
    float e0 = __expf(a0), e1 = __expf(a1);
    float4 u0 = xr0[0], u1 = xr0[1], u2 = xr0[2], u3 = xr0[3];
    float4 u4 = xr0[4], u5 = xr0[5], u6 = xr0[6], u7 = xr0[7];
    float4 w0 = xr1[0], w1 = xr1[1], w2 = xr1[2], w3 = xr1[3];
    float4 w4 = xr1[4], w5 = xr1[5], w6 = xr1[6], w7 = xr1[7];
    acc[0].x = fmaf(e1, w0.x, fmaf(e0, u0.x, acc[0].x));
    acc[0].y = fmaf(e1, w0.y, fmaf(e0, u0.y, acc[0].y));
    acc[0].z = fmaf(e1, w0.z, fmaf(e0, u0.z, acc[0].z));
    acc[0].w = fmaf(e1, w0.w, fmaf(e0, u0.w, acc[0].w));
    acc[1].x = fmaf(e1, w1.x, fmaf(e0, u1.x, acc[1].x));
    acc[1].y = fmaf(e1, w1.y, fmaf(e0, u1.y, acc[1].y));
    acc[1].z = fmaf(e1, w1.z, fmaf(e0, u1.z, acc[1].z));
    acc[1].w = fmaf(e1, w1.w, fmaf(e0, u1.w, acc[1].w));
    acc[2].x = fmaf(e1, w2.x, fmaf(e0, u2.x, acc[2].x));
    acc[2].y = fmaf(e1, w2.y, fmaf(e0, u2.y, acc[2].y));
    acc[2].z = fmaf(e1, w2.z, fmaf(e0, u2.z, acc[2].z));
    acc[2].w = fmaf(e1, w2.w, fmaf(e0, u2.w, acc[2].w));
    acc[3].x = fmaf(e1, w3.x, fmaf(e0, u3.x, acc[3].x));
    acc[3].y = fmaf(e1, w3.y, fmaf(e0, u3.y, acc[3].y));
    acc[3].z = fmaf(e1, w3.z, fmaf(e0, u3.z, acc[3].z));
    acc[3].w = fmaf(e1, w3.w, fmaf(e0, u3.w, acc[3].w));
    acc[4].x = fmaf(e1, w4.x, fmaf(e0, u4.x, acc[4].x));
    acc[4].y = fmaf(e1, w4.y, fmaf(e0, u4.y, acc[4].y));
    acc[4].z = fmaf(e1, w4.z, fmaf(e0, u4.z, acc[4].z));
    acc[4].w = fmaf(e1, w4.w, fmaf(e0, u4.w, acc[4].w));
    acc[5].x = fmaf(e1, w5.x, fmaf(e0, u5.x, acc[5].x));
    acc[5].y = fmaf(e1, w5.y, fmaf(e0, u5.y, acc[5].y));
    acc[5].z = fmaf(e1, w5.z, fmaf(e0, u5.z, acc[5].z));
    acc[5].w = fmaf(e1, w5.w, fmaf(e0, u5.w, acc[5].w));
    acc[6].x = fmaf(e1, w6.x, fmaf(e0, u6.x, acc[6].x));
    acc[6].y = fmaf(e1, w6.y, fmaf(e0, u6.y, acc[6].y));
    acc[6].z = fmaf(e1, w6.z, fmaf(e0, u6.z, acc[6].z));
    acc[6].w = fmaf(e1, w6.w, fmaf(e0, u6.w, acc[6].w));
    acc[7].x = fmaf(e1, w7.x, fmaf(e0, u7.x, acc[7].x));
    acc[7].y = fmaf(e1, w7.y, fmaf(e0, u7.y, acc[7].y));
    acc[7].z = fmaf(e1, w7.z, fmaf(e0, u7.z, acc[7].z));
    acc[7].w = fmaf(e1, w7.w, fmaf(e0, u7.w, acc[7].w));
    den += e0 + e1;
  }
  if (v <= end) {                                 // 1 leftover (edge or self-loop)
    int s = (v < end) ? csr[v] : n;
    float a = alst[(size_t)s * 8] + adv;
    a = fmaxf(a, 0.2f * a);
    float e = __expf(a);
    const float4* xr = x4t + (size_t)s * 8;
    #pragma unroll
    for (int q = 0; q < 8; ++q) {
      float4 xv = xr[q];
      acc[q].x = fmaf(e, xv.x, acc[q].x);
      acc[q].y = fmaf(e, xv.y, acc[q].y);
      acc[q].z = fmaf(e, xv.z, acc[q].z);
      acc[q].w = fmaf(e, xv.w, acc[q].w);
    }
    den += e;
  }
  float4* ao = (float4*)(aggx + ((size_t)t * NN + n) * 256 + h * 32);
  #pragma unroll
  for (int q = 0; q < 8; ++q) ao[q] = acc[q];
  den1[((size_t)t * NN + n) * 8 + h] = den;
}

// ---------------- dense epilogue: 16-node tiles, 5 tiles/block, weights resident -----------
// launch_bounds(256,1) (VGPR cap 256; ~180 used) so weights truly live in registers,
// and a 5-tile loop per block so the one-time weight load amortizes 5x. Grid 2000.

#define PTILES 5

__global__ __launch_bounds__(256, 1) void k_post(const float* __restrict__ aggx,
    const float* __restrict__ den1, const float* __restrict__ W1T, const float* __restrict__ b1,
    const float* __restrict__ W2T, const float* __restrict__ as2, const float* __restrict__ ad2,
    float* __restrict__ h2, float* __restrict__ al2s, float* __restrict__ al2d) {
  __shared__ float aggs[16 * 256];   // phase-2 input; aliased as part[8][16][32] in phase 3
  __shared__ float rels[16 * 256];
  __shared__ float dens[16 * 8];     // INVERSE denominators
  float* part = aggs;                // 8*16*32 == 16*256 floats exactly
  int tid = threadIdx.x;

  int u = tid & 127, grp = tid >> 7;
  int j0 = 2 * u;
  int hj = j0 >> 5;
  // one-time per block: weights + biases into registers (amortized over PTILES tiles)
  float4 w1a[8], w1b[8];
  const float4* w1p = (const float4*)(W1T + j0 * 32);
  #pragma unroll
  for (int q8 = 0; q8 < 8; ++q8) { w1a[q8] = w1p[q8]; w1b[q8] = w1p[q8 + 8]; }
  float bj0 = b1[j0], bj1 = b1[j0 + 1];
  int q = u >> 4, fp = u & 15, f0 = 2 * fp;
  float4 w2a[8], w2b[8];
  const float4* w2pa = (const float4*)(W2T + f0 * 256 + q * 32);
  const float4* w2pb = (const float4*)(W2T + (f0 + 1) * 256 + q * 32);
  #pragma unroll
  for (int q8 = 0; q8 < 8; ++q8) { w2a[q8] = w2pa[q8]; w2b[q8] = w2pb[q8]; }
  float as2f = as2[tid & 31], ad2f = ad2[tid & 31];

  for (int it = 0; it < PTILES; ++it) {
    int tile = blockIdx.x * PTILES + it;
    int t = tile & 7;
    int n0 = (tile >> 3) * 16;

    if (it > 0) __syncthreads();     // part/dens reads of prev tile done before overwrite

    const float4* ag4 = (const float4*)(aggx + ((size_t)t * NN + n0) * 256);
    float4* as4 = (float4*)aggs;
    #pragma unroll
    for (int k = 0; k < 4; ++k) as4[tid + k * 256] = ag4[tid + k * 256];
    if (tid < 128) dens[tid] = 1.f / den1[((size_t)t * NN + n0) * 8 + tid];
    __syncthreads();

    // phase 2: rows grp*8..+7, columns j0, j0+1 (aggs reads shared by both columns)
    #pragma unroll
    for (int g = 0; g < 8; ++g) {
      int row = grp * 8 + g;
      const float4* ar4 = (const float4*)(aggs + row * 256 + hj * 32);
      float a0 = 0.f, a1 = 0.f;
      #pragma unroll
      for (int k4 = 0; k4 < 8; ++k4) {
        float4 av = ar4[k4];
        a0 = fmaf(av.x, w1a[k4].x, fmaf(av.y, w1a[k4].y,
             fmaf(av.z, w1a[k4].z, fmaf(av.w, w1a[k4].w, a0))));
        a1 = fmaf(av.x, w1b[k4].x, fmaf(av.y, w1b[k4].y,
             fmaf(av.z, w1b[k4].z, fmaf(av.w, w1b[k4].w, a1))));
      }
      float invd = dens[row * 8 + hj];
      float2 r;
      r.x = fmaxf(fmaf(a0, invd, bj0), 0.f);
      r.y = fmaxf(fmaf(a1, invd, bj1), 0.f);
      *(float2*)(rels + row * 256 + j0) = r;
    }
    __syncthreads();   // rels ready; aggs dead -> reuse as part

    // phase 3: q-split over K (8 chunks of 32), columns f0, f0+1
    #pragma unroll
    for (int g = 0; g < 8; ++g) {
      int row = grp * 8 + g;
      const float4* r4 = (const float4*)(rels + row * 256 + q * 32);
      float a0 = 0.f, a1 = 0.f;
      #pragma unroll
      for (int jj = 0; jj < 8; ++jj) {
        float4 a4 = r4[jj];
        a0 = fmaf(a4.x, w2a[jj].x, fmaf(a4.y, w2a[jj].y,
             fmaf(a4.z, w2a[jj].z, fmaf(a4.w, w2a[jj].w, a0))));
        a1 = fmaf(a4.x, w2b[jj].x, fmaf(a4.y, w2b[jj].y,
             fmaf(a4.z, w2b[jj].z, fmaf(a4.w, w2b[jj].w, a1))));
      }
      float2 pr; pr.x = a0; pr.y = a1;
      *(float2*)(part + q * 512 + row * 32 + f0) = pr;
    }
    __syncthreads();

    // reduce over q + h2 write + layer-2 logits
    #pragma unroll
    for (int rep = 0; rep < 2; ++rep) {
      int row = (tid >> 5) + rep * 8;
      int ff = tid & 31;
      float v = 0.f;
      #pragma unroll
      for (int qq = 0; qq < 8; ++qq) v += part[qq * 512 + row * 32 + ff];
      int nn = n0 + row;
      h2[((size_t)t * NN + nn) * CD + ff] = v;
      float vs = v * as2f, vd = v * ad2f;
      #pragma unroll
      for (int m = 1; m < 32; m <<= 1) {
        vs += __shfl_xor(vs, m, 64);
        vd += __shfl_xor(vd, m, 64);
      }
      if (ff == 0) {
        al2s[(size_t)t * NN + nn] = vs;
        al2d[(size_t)t * NN + nn] = vd;
      }
    }
  }
}

// ---------------- layer-2 aggregation, ALL t in one wave: lane=(t, f-quad), 2-edge unroll ---
// (256,4): cap 64 (was (256,8) -> cap 32, likely squeezing the 2-edge staging).

__global__ __launch_bounds__(256, 4) void k_agg2(const float* __restrict__ h2,
    const float* __restrict__ al2s, const float* __restrict__ al2d,
    const int* __restrict__ rowptr, const int* __restrict__ csr,
    const float* __restrict__ b2, float* __restrict__ out) {
  int tid = threadIdx.x;
  int wv = tid >> 6, lane = tid & 63;
  int t = lane >> 3, p = lane & 7;
  int n = blockIdx.x * 4 + wv;
  const float* alst = al2s + (size_t)t * NN;
  float adv = al2d[(size_t)t * NN + n];
  const float4* h24 = (const float4*)h2 + (size_t)t * NN * 8 + p;
  float4 b4 = ((const float4*)b2)[p];
  float4 acc = make_float4(0.f, 0.f, 0.f, 0.f);
  float den = 0.f;
  int beg = rowptr[n], end = rowptr[n + 1];
  int v = beg;
  for (; v + 1 <= end; v += 2) {
    int s0 = csr[v];
    int s1 = (v + 1 < end) ? csr[v + 1] : n;
    float a0 = alst[s0] + adv;
    float a1 = alst[s1] + adv;
    float4 u = h24[(size_t)s0 * 8];
    float4 w = h24[(size_t)s1 * 8];
    a0 = fmaxf(a0, 0.2f * a0);
    a1 = fmaxf(a1, 0.2f * a1);
    float e0 = __expf(a0), e1 = __expf(a1);
    acc.x = fmaf(e1, w.x, fmaf(e0, u.x, acc.x));
    acc.y = fmaf(e1, w.y, fmaf(e0, u.y, acc.y));
    acc.z = fmaf(e1, w.z, fmaf(e0, u.z, acc.z));
    acc.w = fmaf(e1, w.w, fmaf(e0, u.w, acc.w));
    den += e0 + e1;
  }
  if (v <= end) {
    int s = (v < end) ? csr[v] : n;
    float a = alst[s] + adv;
    a = fmaxf(a, 0.2f * a);
    float e = __expf(a);
    float4 u = h24[(size_t)s * 8];
    acc.x = fmaf(e, u.x, acc.x);
    acc.y = fmaf(e, u.y, acc.y);
    acc.z = fmaf(e, u.z, acc.z);
    acc.w = fmaf(e, u.w, acc.w);
    den += e;
  }
  float inv = 1.f / den;
  float4 o;
  o.x = fmaf(acc.x, inv, b4.x);
  o.y = fmaf(acc.y, inv, b4.y);
  o.z = fmaf(acc.z, inv, b4.z);
  o.w = fmaf(acc.w, inv, b4.w);
  ((float4*)out)[((size_t)t * NN + n) * 8 + p] = o;
}

// ---------------- LSTM, all t in one kernel: weights in VGPRs, h/c in LDS ------------------

__global__ __launch_bounds__(256) void k_lstm_all(const float* __restrict__ agg2o,
    const float* __restrict__ w_ih, const float* __restrict__ w_hh,
    const float* __restrict__ b_ih, const float* __restrict__ b_hh,
    float* __restrict__ out) {
  __shared__ float xs[16 * 32], hs[16 * 32], cs[16 * 32], pre[16 * 128];
  int tid = threadIdx.x;
  int slot = tid >> 7;
  int r = tid & 127;
  float4 wi[8], wh[8];
  const float4* wi4 = (const float4*)(w_ih + r * 32);
  const float4* wh4 = (const float4*)(w_hh + r * 32);
  #pragma unroll
  for (int q = 0; q < 8; ++q) { wi[q] = wi4[q]; wh[q] = wh4[q]; }
  float bias = b_ih[r] + b_hh[r];
  int base = blockIdx.x * 16;
  for (int i = tid; i < 512; i += 256) { hs[i] = 0.f; cs[i] = 0.f; }
  for (int t = 0; t < TT; ++t) {
    for (int i = tid; i < 512; i += 256) xs[i] = agg2o[(size_t)t * NN * 32 + base * 32 + i];
    __syncthreads();
    #pragma unroll
    for (int g = 0; g < 8; ++g) {
      int nl = slot * 8 + g;
      const float4* xv4 = (const float4*)(xs + nl * 32);
      const float4* hv4 = (const float4*)(hs + nl * 32);
      float acc = bias;
      #pragma unroll
      for (int q = 0; q < 8; ++q) {
        float4 a = xv4[q], b = hv4[q];
        acc = fmaf(a.x, wi[q].x, acc);
        acc = fmaf(a.y, wi[q].y, acc);
        acc = fmaf(a.z, wi[q].z, acc);
        acc = fmaf(a.w, wi[q].w, acc);
        acc = fmaf(b.x, wh[q].x, acc);
        acc = fmaf(b.y, wh[q].y, acc);
        acc = fmaf(b.z, wh[q].z, acc);
        acc = fmaf(b.w, wh[q].w, acc);
      }
      pre[nl * 128 + r] = acc;
    }
    __syncthreads();
    for (int i = tid; i < 512; i += 256) {
      int nl = i >> 5, k = i & 31;
      float ai = pre[nl * 128 + k];
      float af = pre[nl * 128 + 32 + k];
      float ag = pre[nl * 128 + 64 + k];
      float ao = pre[nl * 128 + 96 + k];
      float ii = 1.f / (1.f + __expf(-ai));
      float ff = 1.f / (1.f + __expf(-af));
      float gg = tanhf(ag);
      float oo = 1.f / (1.f + __expf(-ao));
      float cn = fmaf(ff, cs[i], ii * gg);
      float hn = oo * tanhf(cn);
      cs[i] = cn; hs[i] = hn;
      out[(size_t)t * NN * 32 + base * 32 + i] = hn;
    }
  }
}

// ---------------- softmax over nodes, coalesced two-pass ----------------

__global__ __launch_bounds__(256) void k_sm_sum(const float* __restrict__ out, float* __restrict__ sums) {
  int t = blockIdx.y;
  const float4* b4 = (const float4*)(out + ((size_t)t * NN + blockIdx.x * 800) * CD);
  int tid = threadIdx.x;
  float4 s4 = make_float4(0.f, 0.f, 0.f, 0.f);
  for (int i = tid; i < 6400; i += 256) {
    float4 v = b4[i];
    s4.x += __expf(v.x); s4.y += __expf(v.y);
    s4.z += __expf(v.z); s4.w += __expf(v.w);
  }
  __shared__ float4 red[256];
  red[tid] = s4;
  __syncthreads();
  for (int off = 128; off >= 8; off >>= 1) {
    if (tid < off) {
      float4 o = red[tid + off];
      red[tid].x += o.x; red[tid].y += o.y; red[tid].z += o.z; red[tid].w += o.w;
    }
    __syncthreads();
  }
  if (tid < 8) {
    float4 v = red[tid];
    int c0 = tid * 4;
    atomicAdd(&sums[t * CD + c0 + 0], v.x);
    atomicAdd(&sums[t * CD + c0 + 1], v.y);
    atomicAdd(&sums[t * CD + c0 + 2], v.z);
    atomicAdd(&sums[t * CD + c0 + 3], v.w);
  }
}

__global__ __launch_bounds__(256) void k_sm_scale(float* __restrict__ out, const float* __restrict__ sums) {
  int t = blockIdx.y;
  __shared__ float inv[CD];
  int tid = threadIdx.x;
  if (tid < CD) inv[tid] = 1.f / sums[t * CD + tid];
  __syncthreads();
  float4* b4 = (float4*)(out + ((size_t)t * NN + blockIdx.x * 800) * CD);
  for (int i = tid; i < 6400; i += 256) {
    float4 v = b4[i];
    int c0 = (4 * i) & 31;
    v.x = __expf(v.x) * inv[c0];
    v.y = __expf(v.y) * inv[c0 + 1];
    v.z = __expf(v.z) * inv[c0 + 2];
    v.w = __expf(v.w) * inv[c0 + 3];
    b4[i] = v;
  }
}

// ---------------- launch ----------------

extern "C" void kernel_launch(void* const* d_in, const int* in_sizes, int n_in,
                              void* d_out, int out_size, void* d_ws, size_t ws_size,
                              hipStream_t stream) {
  const float* x   = (const float*)d_in[0];
  const float* W1  = (const float*)d_in[1];
  const float* as1 = (const float*)d_in[2];
  const float* ad1 = (const float*)d_in[3];
  const float* b1  = (const float*)d_in[4];
  const float* W2  = (const float*)d_in[5];
  const float* as2 = (const float*)d_in[6];
  const float* ad2 = (const float*)d_in[7];
  const float* b2  = (const float*)d_in[8];
  const float* wih = (const float*)d_in[9];
  const float* whh = (const float*)d_in[10];
  const float* bih = (const float*)d_in[11];
  const float* bhh = (const float*)d_in[12];
  const int*   ei  = (const int*)d_in[13];
  const int* srcp = ei;
  const int* dstp = ei + NE;
  float* out = (float*)d_out;

  float* ws = (float*)d_ws;
  float* aggx  = ws;  ws += (size_t)TT * NN * 256;   // 164 MB
  float* den1  = ws;  ws += (size_t)TT * NN * 8;
  float* al1s  = ws;  ws += (size_t)TT * NN * 8;
  float* al1d  = ws;  ws += (size_t)TT * NN * 8;
  float* h2    = ws;  ws += (size_t)TT * NN * CD;
  float* al2s  = ws;  ws += (size_t)TT * NN;
  float* al2d  = ws;  ws += (size_t)TT * NN;
  float* agg2o = ws;  ws += (size_t)TT * NN * CD;
  float* sums  = ws;  ws += TT * CD;
  float* wsrc  = ws;  ws += 256;
  float* wdst  = ws;  ws += 256;
  float* W1T   = ws;  ws += D1 * 32;
  float* W2T   = ws;  ws += 32 * D1;
  int* rowptr = (int*)ws;
  int* fill   = rowptr + NN + 1;
  int* csr    = fill + NN;
  int* deg    = csr + NE;

  hipMemsetAsync(sums, 0, TT * CD * sizeof(float), stream);
  hipMemsetAsync(deg, 0, NN * sizeof(int), stream);

  k_deg<<<(NE + 255) / 256, 256, 0, stream>>>(dstp, deg);
  k_scan<<<1, 1024, 0, stream>>>(deg, rowptr, fill);
  k_fill<<<(NE + 255) / 256, 256, 0, stream>>>(srcp, dstp, fill, csr);
  k_prew<<<1, 256, 0, stream>>>(W1, as1, ad1, W2, wsrc, wdst, W1T, W2T);

  k_logits8<<<(NN / 32) * TT, 256, 0, stream>>>(x, wsrc, wdst, al1s, al1d);
  k_gat1<<<NN / 4, 256, 0, stream>>>(x, al1s, al1d, rowptr, csr, aggx, den1);
  k_post<<<(NN / 16) * TT / PTILES, 256, 0, stream>>>(aggx, den1, W1T, b1, W2T, as2, ad2,
                                                      h2, al2s, al2d);
  k_agg2<<<NN / 4, 256, 0, stream>>>(h2, al2s, al2d, rowptr, csr, b2, agg2o);
  k_lstm_all<<<NN / 16, 256, 0, stream>>>(agg2o, wih, whh, bih, bhh, out);

  k_sm_sum<<<dim3(25, TT), 256, 0, stream>>>(out, sums);
  k_sm_scale<<<dim3(25, TT), 256, 0, stream>>>(out, sums);
}